// Round 2
// baseline (325.654 us; speedup 1.0000x reference)
//
#include <hip/hip_runtime.h>

// Problem constants
#define V_N 256
#define T_N 256
#define K_N 36
#define L_N 32
#define D_N 1024
#define MROWS (V_N * K_N)         // 9216 (UNPADDED)
#define NROWS (T_N * L_N)         // 8192
#define BM 128
#define BN 128
#define BK 64                     // bf16 elems per K-step
#define KSTEPS (D_N / BK)         // 16

typedef __attribute__((ext_vector_type(8))) short bf16x8;
typedef __attribute__((ext_vector_type(4))) float f32x4;

// fp32 -> bf16 RNE, branchless
__device__ __forceinline__ ushort f2bf(float x) {
  union { float f; unsigned int u; } c; c.f = x;
  unsigned int r = c.u + 0x7FFFu + ((c.u >> 16) & 1u);
  return (ushort)(r >> 16);
}

// ---------------- conversion kernel: fp32 -> bf16 workspace (flat cast) -----
__global__ void cvt_cast(const float* __restrict__ imgs, const float* __restrict__ caps,
                         ushort* __restrict__ aws, ushort* __restrict__ bws) {
  const int AQ = MROWS * (D_N / 4);
  const int BQ = NROWS * (D_N / 4);
  const int total = AQ + BQ;
  for (int q = blockIdx.x * blockDim.x + threadIdx.x; q < total;
       q += gridDim.x * blockDim.x) {
    float4 f;
    ushort4* dst;
    if (q < AQ) {
      f = reinterpret_cast<const float4*>(imgs)[q];
      dst = reinterpret_cast<ushort4*>(aws) + q;
    } else {
      f = reinterpret_cast<const float4*>(caps)[q - AQ];
      dst = reinterpret_cast<ushort4*>(bws) + (q - AQ);
    }
    ushort4 u; u.x = f2bf(f.x); u.y = f2bf(f.y); u.z = f2bf(f.z); u.w = f2bf(f.w);
    *dst = u;
  }
}

// ---------------- fused GEMM + square + segmented block-sum -----------------
// S = A*B^T over bf16; out[v,t] += sum of squares of S entries, where
// v = arow/36, t = bcol/32. M is unpadded, so a 16-row C-fragment may span
// one v-boundary -> 2-segment reduce in the epilogue.
// LDS: row-major [rows][BK] bf16 (128B rows), 16B-chunk XOR swizzle
// byte ^= ((row&7)<<4) applied on BOTH staging source addr and ds_read addr.
template <int USE_WS>
__global__ __launch_bounds__(256) void gemm_sq(
    const ushort* __restrict__ aws, const ushort* __restrict__ bws,
    const float* __restrict__ imgs, const float* __restrict__ caps,
    float* __restrict__ out) {
  __shared__ ushort lds[BM * BK + BN * BK];  // 32 KiB
  ushort* ldsA = lds;
  ushort* ldsB = lds + BM * BK;

  const int NBM = MROWS / BM;            // 72
  const int NBN = NROWS / BN;            // 64
  // XCD-aware mapping: XCD x owns a contiguous 9-wide bm band (2.25 MB of A,
  // L2-resident) and sweeps bn fast within it.
  int orig = (int)blockIdx.x;
  int xcd = orig & 7;
  int idx = orig >> 3;                   // 0..(NBM/8)*NBN-1 = 0..575
  int bm = xcd * (NBM / 8) + (idx >> 6); // idx / NBN
  int bn = idx & 63;                     // idx % NBN
  const int row0 = bm * BM;
  const int col0 = bn * BN;

  const int tid  = (int)threadIdx.x;
  const int lane = tid & 63;
  const int wid  = tid >> 6;
  const int wr   = wid >> 1;   // 0..1 (64-row slab)
  const int wc   = wid & 1;    // 0..1 (64-col slab)

  f32x4 acc[4][4];
#pragma unroll
  for (int i = 0; i < 4; ++i)
#pragma unroll
    for (int j = 0; j < 4; ++j) acc[i][j] = (f32x4){0.f, 0.f, 0.f, 0.f};

  for (int kt = 0; kt < KSTEPS; ++kt) {
    if (USE_WS) {
#pragma unroll
      for (int it = 0; it < 4; ++it) {
        int q = it * 256 + tid;            // 16B chunk id
        int r = q >> 3;                    // tile row
        int cb = (q & 7) << 4;             // byte col in 128B row
        int sw = cb ^ ((r & 7) << 4);
        const ushort* ga = aws + (size_t)(row0 + r) * D_N + kt * BK + (sw >> 1);
        __builtin_amdgcn_global_load_lds(
            (const __attribute__((address_space(1))) void*)ga,
            (__attribute__((address_space(3))) void*)(ldsA + q * 8), 16, 0, 0);
      }
#pragma unroll
      for (int it = 0; it < 4; ++it) {
        int q = it * 256 + tid;
        int r = q >> 3;
        int cb = (q & 7) << 4;
        int sw = cb ^ ((r & 7) << 4);
        const ushort* gb = bws + (size_t)(col0 + r) * D_N + kt * BK + (sw >> 1);
        __builtin_amdgcn_global_load_lds(
            (const __attribute__((address_space(1))) void*)gb,
            (__attribute__((address_space(3))) void*)(ldsB + q * 8), 16, 0, 0);
      }
    } else {
      // reg-staged fp32 -> bf16 fallback (no workspace dependency)
#pragma unroll
      for (int it = 0; it < 4; ++it) {
        int q = it * 256 + tid;
        int r = q >> 3;
        int cb = (q & 7) << 4;
        int sw = cb ^ ((r & 7) << 4);
        const float4* src = reinterpret_cast<const float4*>(
            imgs + (size_t)(row0 + r) * D_N + kt * BK + (sw >> 1));
        float4 f0 = src[0], f1 = src[1];
        union { ushort u[8]; int4 v4; } pk;
        pk.u[0] = f2bf(f0.x); pk.u[1] = f2bf(f0.y);
        pk.u[2] = f2bf(f0.z); pk.u[3] = f2bf(f0.w);
        pk.u[4] = f2bf(f1.x); pk.u[5] = f2bf(f1.y);
        pk.u[6] = f2bf(f1.z); pk.u[7] = f2bf(f1.w);
        *reinterpret_cast<int4*>(ldsA + q * 8) = pk.v4;
      }
#pragma unroll
      for (int it = 0; it < 4; ++it) {
        int q = it * 256 + tid;
        int r = q >> 3;
        int cb = (q & 7) << 4;
        int sw = cb ^ ((r & 7) << 4);
        const float4* src = reinterpret_cast<const float4*>(
            caps + (size_t)(col0 + r) * D_N + kt * BK + (sw >> 1));
        float4 f0 = src[0], f1 = src[1];
        union { ushort u[8]; int4 v4; } pk;
        pk.u[0] = f2bf(f0.x); pk.u[1] = f2bf(f0.y);
        pk.u[2] = f2bf(f0.z); pk.u[3] = f2bf(f0.w);
        pk.u[4] = f2bf(f1.x); pk.u[5] = f2bf(f1.y);
        pk.u[6] = f2bf(f1.z); pk.u[7] = f2bf(f1.w);
        *reinterpret_cast<int4*>(ldsB + q * 8) = pk.v4;
      }
    }
    __syncthreads();

#pragma unroll
    for (int ks = 0; ks < 2; ++ks) {
      bf16x8 afr[4], bfr[4];
#pragma unroll
      for (int i = 0; i < 4; ++i) {
        int r = wr * 64 + i * 16 + (lane & 15);
        int kb = ks * 64 + ((lane >> 4) << 4);      // byte offset along K
        int sw = kb ^ ((r & 7) << 4);
        afr[i] = *reinterpret_cast<const bf16x8*>(ldsA + r * BK + (sw >> 1));
      }
#pragma unroll
      for (int j = 0; j < 4; ++j) {
        int r = wc * 64 + j * 16 + (lane & 15);
        int kb = ks * 64 + ((lane >> 4) << 4);
        int sw = kb ^ ((r & 7) << 4);
        bfr[j] = *reinterpret_cast<const bf16x8*>(ldsB + r * BK + (sw >> 1));
      }
#pragma unroll
      for (int i = 0; i < 4; ++i)
#pragma unroll
        for (int j = 0; j < 4; ++j)
          acc[i][j] = __builtin_amdgcn_mfma_f32_16x16x32_bf16(
              afr[i], bfr[j], acc[i][j], 0, 0, 0);
    }
    __syncthreads();
  }

  // Epilogue: cols of a fragment are within one t (16-aligned, L=32); rows may
  // span one v-boundary (K=36). C/D mapping: col=lane&15, row=(lane>>4)*4+reg.
#pragma unroll
  for (int i = 0; i < 4; ++i) {
#pragma unroll
    for (int j = 0; j < 4; ++j) {
      f32x4 a4 = acc[i][j];
      int grow = row0 + wr * 64 + i * 16;       // global A row of frag row 0
      int gcol = col0 + wc * 64 + j * 16;
      int t = gcol >> 5;
      int v0 = grow / K_N;
      int b = (v0 + 1) * K_N;                   // first row of v0+1
      int rbase = grow + ((lane >> 4) << 2);
      float s0 = 0.f, s1 = 0.f;
#pragma unroll
      for (int rg = 0; rg < 4; ++rg) {
        float x = a4[rg];
        float x2 = x * x;
        if (rbase + rg < b) s0 += x2; else s1 += x2;
      }
#pragma unroll
      for (int off = 32; off > 0; off >>= 1) {
        s0 += __shfl_xor(s0, off, 64);
        s1 += __shfl_xor(s1, off, 64);
      }
      if (lane == 0) {
        atomicAdd(out + v0 * T_N + t, s0);
        if (b < grow + 16) atomicAdd(out + (v0 + 1) * T_N + t, s1);
      }
    }
  }
}

extern "C" void kernel_launch(void* const* d_in, const int* in_sizes, int n_in,
                              void* d_out, int out_size, void* d_ws, size_t ws_size,
                              hipStream_t stream) {
  const float* imgs = (const float*)d_in[0];
  const float* caps = (const float*)d_in[1];
  float* out = (float*)d_out;

  hipMemsetAsync(d_out, 0, (size_t)V_N * T_N * sizeof(float), stream);

  const size_t need = (size_t)(MROWS + NROWS) * D_N * sizeof(ushort);  // ~36 MB
  const int nwg = (MROWS / BM) * (NROWS / BN);                         // 4608

  if (ws_size >= need) {
    ushort* aws = (ushort*)d_ws;
    ushort* bws = aws + (size_t)MROWS * D_N;
    cvt_cast<<<2048, 256, 0, stream>>>(imgs, caps, aws, bws);
    gemm_sq<1><<<nwg, 256, 0, stream>>>(aws, bws, imgs, caps, out);
  } else {
    gemm_sq<0><<<nwg, 256, 0, stream>>>(nullptr, nullptr, imgs, caps, out);
  }
}

// Round 3
// 200.363 us; speedup vs baseline: 1.6253x; 1.6253x over previous
//
#include <hip/hip_runtime.h>

// Problem constants
#define V_N 256
#define T_N 256
#define K_N 36
#define L_N 32
#define D_N 1024
#define MROWS (V_N * K_N)         // 9216
#define NROWS (T_N * L_N)         // 8192
#define BM 256
#define BN 256
#define BK 64                     // bf16 elems per K-tile
#define KSTEPS (D_N / BK)         // 16
#define NBM (MROWS / BM)          // 36
#define NBN (NROWS / BN)          // 32
#define NWG (NBM * NBN)           // 1152 (divisible by 8)

typedef __attribute__((ext_vector_type(8))) short bf16x8;
typedef __attribute__((ext_vector_type(4))) float f32x4;

__device__ __forceinline__ ushort f2bf(float x) {
  union { float f; unsigned int u; } c; c.f = x;
  unsigned int r = c.u + 0x7FFFu + ((c.u >> 16) & 1u);
  return (ushort)(r >> 16);
}

// ---------------- conversion kernel: fp32 -> bf16 workspace (flat cast) -----
__global__ void cvt_cast(const float* __restrict__ imgs, const float* __restrict__ caps,
                         ushort* __restrict__ aws, ushort* __restrict__ bws) {
  const int AQ = MROWS * (D_N / 4);
  const int BQ = NROWS * (D_N / 4);
  const int total = AQ + BQ;
  for (int q = blockIdx.x * blockDim.x + threadIdx.x; q < total;
       q += gridDim.x * blockDim.x) {
    float4 f;
    ushort4* dst;
    if (q < AQ) {
      f = reinterpret_cast<const float4*>(imgs)[q];
      dst = reinterpret_cast<ushort4*>(aws) + q;
    } else {
      f = reinterpret_cast<const float4*>(caps)[q - AQ];
      dst = reinterpret_cast<ushort4*>(bws) + (q - AQ);
    }
    ushort4 u; u.x = f2bf(f.x); u.y = f2bf(f.y); u.z = f2bf(f.z); u.w = f2bf(f.w);
    *dst = u;
  }
}

// ---------------- 256x256 deep-pipelined GEMM + square + block-sum ----------
// S = A*B^T (bf16, fp32 acc); out[v,t] += sum of squares, v=arow/36, t=bcol/32.
// Pipeline (race math):
//   - tiles t live in buf[t&1]; tile t's 8 loads/wave issued during tile t-2.
//   - per tile: [compute: 24 ds_read + 64 MFMA] -> lgkmcnt(0)+barrier
//     (all reads of buf[t&1] retired across waves) -> [stage t+2 into
//     buf[t&1]] -> vmcnt(8) (own t+1 loads landed; only t+2's 8 outstanding)
//     -> barrier (everyone's t+1 portion landed) -> next tile.
//   - never vmcnt(0) in the main loop (T4); setprio around MFMA (T5);
//     st-style XOR swizzle byte^=((row&7)<<4) on source+read (T2).
__global__ __launch_bounds__(512, 2) void gemm2(
    const ushort* __restrict__ aws, const ushort* __restrict__ bws,
    float* __restrict__ out) {
  __shared__ ushort lds[2 * 2 * BM * BK];   // 128 KiB: 2 bufs x (A 256x64 + B 256x64)

  int orig = (int)blockIdx.x;
  int wg = (orig & 7) * (NWG / 8) + (orig >> 3);   // bijective XCD swizzle
  const int bm = wg / NBN;
  const int bn = wg % NBN;
  const int row0 = bm * BM;
  const int col0 = bn * BN;

  const int tid  = (int)threadIdx.x;
  const int lane = tid & 63;
  const int wid  = tid >> 6;
  const int wr   = wid >> 2;     // 0..1  -> 128-row slab
  const int wc   = wid & 3;      // 0..3  -> 64-col slab

  // ---- staging: one K-tile (A 256x64 + B 256x64), 8 gload_lds per thread
  auto stage = [&](int kt) {
    ushort* bufA = lds + (kt & 1) * (2 * BM * BK);
    ushort* bufB = bufA + BM * BK;
#pragma unroll
    for (int it = 0; it < 4; ++it) {
      int q = it * 512 + tid;                 // 16B chunk id, wave-contiguous
      int r = q >> 3;
      int sw = ((q & 7) << 4) ^ ((r & 7) << 4);
      const ushort* ga = aws + (size_t)(row0 + r) * D_N + kt * BK + (sw >> 1);
      __builtin_amdgcn_global_load_lds(
          (const __attribute__((address_space(1))) void*)ga,
          (__attribute__((address_space(3))) void*)(bufA + q * 8), 16, 0, 0);
    }
#pragma unroll
    for (int it = 0; it < 4; ++it) {
      int q = it * 512 + tid;
      int r = q >> 3;
      int sw = ((q & 7) << 4) ^ ((r & 7) << 4);
      const ushort* gb = bws + (size_t)(col0 + r) * D_N + kt * BK + (sw >> 1);
      __builtin_amdgcn_global_load_lds(
          (const __attribute__((address_space(1))) void*)gb,
          (__attribute__((address_space(3))) void*)(bufB + q * 8), 16, 0, 0);
    }
  };

  f32x4 acc[8][4];
#pragma unroll
  for (int m = 0; m < 8; ++m)
#pragma unroll
    for (int n = 0; n < 4; ++n) acc[m][n] = (f32x4){0.f, 0.f, 0.f, 0.f};

  const int arow = wr * 128 + (lane & 15);   // A tile row (+m*16)
  const int brow = wc * 64 + (lane & 15);    // B tile row (+n*16)
  const int kb   = (lane >> 4) << 4;         // byte offset within 64B k-slice
  const int swz  = (lane & 7) << 4;          // row&7 == lane&7 for our rows

  auto compute = [&](int kt) {
    const ushort* bufA = lds + (kt & 1) * (2 * BM * BK);
    const ushort* bufB = bufA + BM * BK;
#pragma unroll
    for (int ks = 0; ks < 2; ++ks) {
      const int sw = (ks * 64 + kb) ^ swz;   // swizzled byte col in 128B row
      bf16x8 af[8], bf[4];
#pragma unroll
      for (int m = 0; m < 8; ++m)
        af[m] = *reinterpret_cast<const bf16x8*>(bufA + (arow + m * 16) * BK + (sw >> 1));
#pragma unroll
      for (int n = 0; n < 4; ++n)
        bf[n] = *reinterpret_cast<const bf16x8*>(bufB + (brow + n * 16) * BK + (sw >> 1));
      __builtin_amdgcn_s_setprio(1);
#pragma unroll
      for (int m = 0; m < 8; ++m)
#pragma unroll
        for (int n = 0; n < 4; ++n)
          acc[m][n] = __builtin_amdgcn_mfma_f32_16x16x32_bf16(af[m], bf[n], acc[m][n], 0, 0, 0);
      __builtin_amdgcn_s_setprio(0);
    }
  };

  // ---- prologue: stage tiles 0,1; wait tile 0 landed
  stage(0);
  stage(1);
  asm volatile("s_waitcnt vmcnt(8)" ::: "memory");
  __builtin_amdgcn_sched_barrier(0);
  __builtin_amdgcn_s_barrier();
  __builtin_amdgcn_sched_barrier(0);

  // ---- main loop: t = 0..13
  for (int t = 0; t < KSTEPS - 2; ++t) {
    compute(t);
    asm volatile("s_waitcnt lgkmcnt(0)" ::: "memory");
    __builtin_amdgcn_sched_barrier(0);
    __builtin_amdgcn_s_barrier();
    __builtin_amdgcn_sched_barrier(0);
    stage(t + 2);
    asm volatile("s_waitcnt vmcnt(8)" ::: "memory");
    __builtin_amdgcn_sched_barrier(0);
    __builtin_amdgcn_s_barrier();
    __builtin_amdgcn_sched_barrier(0);
  }
  // ---- t = 14: no stage; ensure tile 15 fully landed
  compute(KSTEPS - 2);
  asm volatile("s_waitcnt vmcnt(0)" ::: "memory");
  __builtin_amdgcn_sched_barrier(0);
  __builtin_amdgcn_s_barrier();
  __builtin_amdgcn_sched_barrier(0);
  // ---- t = 15
  compute(KSTEPS - 1);

  // ---- epilogue: squared block-sums. C/D: col=lane&15, row=(lane>>4)*4+reg.
  // n-pairs (np) share the same t (32 cols); rows may span one v boundary.
#pragma unroll
  for (int m = 0; m < 8; ++m) {
    int grow = row0 + wr * 128 + m * 16;
    int v0 = grow / K_N;
    int b = (v0 + 1) * K_N;
    int rb = grow + ((lane >> 4) << 2);
#pragma unroll
    for (int np = 0; np < 2; ++np) {
      float s0 = 0.f, s1 = 0.f;
#pragma unroll
      for (int nn = 0; nn < 2; ++nn) {
        f32x4 a4 = acc[m][np * 2 + nn];
#pragma unroll
        for (int rg = 0; rg < 4; ++rg) {
          float x = a4[rg];
          float x2 = x * x;
          if (rb + rg < b) s0 += x2; else s1 += x2;
        }
      }
#pragma unroll
      for (int off = 32; off > 0; off >>= 1) {
        s0 += __shfl_xor(s0, off, 64);
        s1 += __shfl_xor(s1, off, 64);
      }
      if (lane == 0) {
        int tcol = (col0 + wc * 64 + np * 32) >> 5;
        atomicAdd(out + v0 * T_N + tcol, s0);
        if (grow + 16 > b) atomicAdd(out + (v0 + 1) * T_N + tcol, s1);
      }
    }
  }
}

// ---------------- fallback (no workspace): R1's 128x128 reg-staged kernel ---
__global__ __launch_bounds__(256) void gemm_fb(
    const float* __restrict__ imgs, const float* __restrict__ caps,
    float* __restrict__ out) {
  __shared__ ushort lds[128 * 64 + 128 * 64];
  ushort* ldsA = lds;
  ushort* ldsB = lds + 128 * 64;
  const int NBMf = MROWS / 128, NBNf = NROWS / 128;
  int orig = (int)blockIdx.x;
  int xcd = orig & 7;
  int idx = orig >> 3;
  int bm = xcd * (NBMf / 8) + (idx / NBNf);
  int bn = idx % NBNf;
  const int row0 = bm * 128, col0 = bn * 128;
  const int tid = (int)threadIdx.x, lane = tid & 63, wid = tid >> 6;
  const int wr = wid >> 1, wc = wid & 1;
  f32x4 acc[4][4];
#pragma unroll
  for (int i = 0; i < 4; ++i)
#pragma unroll
    for (int j = 0; j < 4; ++j) acc[i][j] = (f32x4){0.f, 0.f, 0.f, 0.f};
  for (int kt = 0; kt < KSTEPS; ++kt) {
#pragma unroll
    for (int it = 0; it < 4; ++it) {
      int q = it * 256 + tid;
      int r = q >> 3;
      int sw = ((q & 7) << 4) ^ ((r & 7) << 4);
      const float4* src = reinterpret_cast<const float4*>(
          imgs + (size_t)(row0 + r) * D_N + kt * BK + (sw >> 1));
      float4 f0 = src[0], f1 = src[1];
      union { ushort u[8]; int4 v4; } pk;
      pk.u[0] = f2bf(f0.x); pk.u[1] = f2bf(f0.y); pk.u[2] = f2bf(f0.z); pk.u[3] = f2bf(f0.w);
      pk.u[4] = f2bf(f1.x); pk.u[5] = f2bf(f1.y); pk.u[6] = f2bf(f1.z); pk.u[7] = f2bf(f1.w);
      *reinterpret_cast<int4*>(ldsA + q * 8) = pk.v4;
    }
#pragma unroll
    for (int it = 0; it < 4; ++it) {
      int q = it * 256 + tid;
      int r = q >> 3;
      int sw = ((q & 7) << 4) ^ ((r & 7) << 4);
      const float4* src = reinterpret_cast<const float4*>(
          caps + (size_t)(col0 + r) * D_N + kt * BK + (sw >> 1));
      float4 f0 = src[0], f1 = src[1];
      union { ushort u[8]; int4 v4; } pk;
      pk.u[0] = f2bf(f0.x); pk.u[1] = f2bf(f0.y); pk.u[2] = f2bf(f0.z); pk.u[3] = f2bf(f0.w);
      pk.u[4] = f2bf(f1.x); pk.u[5] = f2bf(f1.y); pk.u[6] = f2bf(f1.z); pk.u[7] = f2bf(f1.w);
      *reinterpret_cast<int4*>(ldsB + q * 8) = pk.v4;
    }
    __syncthreads();
#pragma unroll
    for (int ks = 0; ks < 2; ++ks) {
      bf16x8 afr[4], bfr[4];
#pragma unroll
      for (int i = 0; i < 4; ++i) {
        int r = wr * 64 + i * 16 + (lane & 15);
        int sw = (ks * 64 + (((lane >> 4) << 4))) ^ ((r & 7) << 4);
        afr[i] = *reinterpret_cast<const bf16x8*>(ldsA + r * BK + (sw >> 1));
      }
#pragma unroll
      for (int j = 0; j < 4; ++j) {
        int r = wc * 64 + j * 16 + (lane & 15);
        int sw = (ks * 64 + (((lane >> 4) << 4))) ^ ((r & 7) << 4);
        bfr[j] = *reinterpret_cast<const bf16x8*>(ldsB + r * BK + (sw >> 1));
      }
#pragma unroll
      for (int i = 0; i < 4; ++i)
#pragma unroll
        for (int j = 0; j < 4; ++j)
          acc[i][j] = __builtin_amdgcn_mfma_f32_16x16x32_bf16(afr[i], bfr[j], acc[i][j], 0, 0, 0);
    }
    __syncthreads();
  }
#pragma unroll
  for (int i = 0; i < 4; ++i) {
#pragma unroll
    for (int j = 0; j < 4; ++j) {
      f32x4 a4 = acc[i][j];
      int grow = row0 + wr * 64 + i * 16;
      int gcol = col0 + wc * 64 + j * 16;
      int t = gcol >> 5;
      int v0 = grow / K_N;
      int b = (v0 + 1) * K_N;
      int rbase = grow + ((lane >> 4) << 2);
      float s0 = 0.f, s1 = 0.f;
#pragma unroll
      for (int rg = 0; rg < 4; ++rg) {
        float x = a4[rg];
        float x2 = x * x;
        if (rbase + rg < b) s0 += x2; else s1 += x2;
      }
#pragma unroll
      for (int off = 32; off > 0; off >>= 1) {
        s0 += __shfl_xor(s0, off, 64);
        s1 += __shfl_xor(s1, off, 64);
      }
      if (lane == 0) {
        atomicAdd(out + v0 * T_N + t, s0);
        if (b < grow + 16) atomicAdd(out + (v0 + 1) * T_N + t, s1);
      }
    }
  }
}

extern "C" void kernel_launch(void* const* d_in, const int* in_sizes, int n_in,
                              void* d_out, int out_size, void* d_ws, size_t ws_size,
                              hipStream_t stream) {
  const float* imgs = (const float*)d_in[0];
  const float* caps = (const float*)d_in[1];
  float* out = (float*)d_out;

  hipMemsetAsync(d_out, 0, (size_t)V_N * T_N * sizeof(float), stream);

  const size_t need = (size_t)(MROWS + NROWS) * D_N * sizeof(ushort);  // ~36 MB

  if (ws_size >= need) {
    ushort* aws = (ushort*)d_ws;
    ushort* bws = aws + (size_t)MROWS * D_N;
    cvt_cast<<<2048, 256, 0, stream>>>(imgs, caps, aws, bws);
    gemm2<<<NWG, 512, 0, stream>>>(aws, bws, out);
  } else {
    const int nwg = (MROWS / 128) * (NROWS / 128);
    gemm_fb<<<nwg, 256, 0, stream>>>(imgs, caps, out);
  }
}

// Round 4
// 197.753 us; speedup vs baseline: 1.6468x; 1.0132x over previous
//
#include <hip/hip_runtime.h>

// Problem constants
#define V_N 256
#define T_N 256
#define K_N 36
#define L_N 32
#define D_N 1024
#define MROWS (V_N * K_N)         // 9216
#define NROWS (T_N * L_N)         // 8192
#define BM 256
#define BN 256
#define BK 64                     // bf16 elems per K-tile
#define KSTEPS (D_N / BK)         // 16
#define NBM (MROWS / BM)          // 36
#define NBN (NROWS / BN)          // 32
#define NWG (NBM * NBN)           // 1152 (divisible by 8)

typedef __attribute__((ext_vector_type(8))) short bf16x8;
typedef __attribute__((ext_vector_type(4))) float f32x4;

__device__ __forceinline__ ushort f2bf(float x) {
  union { float f; unsigned int u; } c; c.f = x;
  unsigned int r = c.u + 0x7FFFu + ((c.u >> 16) & 1u);
  return (ushort)(r >> 16);
}

// ---------------- conversion kernel: fp32 -> bf16 workspace (flat cast) -----
__global__ void cvt_cast(const float* __restrict__ imgs, const float* __restrict__ caps,
                         ushort* __restrict__ aws, ushort* __restrict__ bws) {
  const int AQ = MROWS * (D_N / 4);
  const int BQ = NROWS * (D_N / 4);
  const int total = AQ + BQ;
  for (int q = blockIdx.x * blockDim.x + threadIdx.x; q < total;
       q += gridDim.x * blockDim.x) {
    float4 f;
    ushort4* dst;
    if (q < AQ) {
      f = reinterpret_cast<const float4*>(imgs)[q];
      dst = reinterpret_cast<ushort4*>(aws) + q;
    } else {
      f = reinterpret_cast<const float4*>(caps)[q - AQ];
      dst = reinterpret_cast<ushort4*>(bws) + (q - AQ);
    }
    ushort4 u; u.x = f2bf(f.x); u.y = f2bf(f.y); u.z = f2bf(f.z); u.w = f2bf(f.w);
    *dst = u;
  }
}

// ---------------- 256x256 interleaved-pipeline GEMM + square + block-sum ----
// S = A*B^T (bf16, fp32 acc); out[v,t] += sum of squares, v=arow/36, t=bcol/32.
// Distance-2 parity pipeline (race math identical to R2):
//   tile t lives in buf[t&1]; its 8 loads/wave were issued during tile t-2.
//   Per tile: [24 ds_read (quadrant order) overlapped with MFMA Q0,Q1,Q2]
//   -> lgkmcnt(0)+barrier (all reads of buf[t&1] retired, write-hazard gate)
//   -> [stage t+2 into buf[t&1] (8 loads) || MFMA Q3]
//   -> vmcnt(8) (own t+1 loads landed; only t+2's 8 outstanding) -> barrier.
//   Never vmcnt(0) in the main loop (T4); setprio per MFMA quadrant (T5);
//   XOR swizzle byte^=((row&7)<<4) on stage-source + ds_read (T2).
__global__ __launch_bounds__(512, 2) void gemm2(
    const ushort* __restrict__ aws, const ushort* __restrict__ bws,
    float* __restrict__ out) {
  __shared__ ushort lds[2 * 2 * BM * BK];   // 128 KiB: 2 bufs x (A 256x64 + B 256x64)

  int orig = (int)blockIdx.x;
  int wg = (orig & 7) * (NWG / 8) + (orig >> 3);   // bijective XCD swizzle
  const int bm = wg / NBN;
  const int bn = wg % NBN;
  const int row0 = bm * BM;
  const int col0 = bn * BN;

  const int tid  = (int)threadIdx.x;
  const int lane = tid & 63;
  const int wid  = tid >> 6;
  const int wr   = wid >> 2;     // 0..1  -> 128-row slab
  const int wc   = wid & 3;      // 0..3  -> 64-col slab

  // ---- staging halves: A (4 loads/thread) and B (4 loads/thread)
  auto stageA = [&](int kt) {
    ushort* bufA = lds + (kt & 1) * (2 * BM * BK);
#pragma unroll
    for (int it = 0; it < 4; ++it) {
      int q = it * 512 + tid;                 // 16B chunk id, wave-contiguous
      int r = q >> 3;
      int sw = ((q & 7) << 4) ^ ((r & 7) << 4);
      const ushort* ga = aws + (size_t)(row0 + r) * D_N + kt * BK + (sw >> 1);
      __builtin_amdgcn_global_load_lds(
          (const __attribute__((address_space(1))) void*)ga,
          (__attribute__((address_space(3))) void*)(bufA + q * 8), 16, 0, 0);
    }
  };
  auto stageB = [&](int kt) {
    ushort* bufB = lds + (kt & 1) * (2 * BM * BK) + BM * BK;
#pragma unroll
    for (int it = 0; it < 4; ++it) {
      int q = it * 512 + tid;
      int r = q >> 3;
      int sw = ((q & 7) << 4) ^ ((r & 7) << 4);
      const ushort* gb = bws + (size_t)(col0 + r) * D_N + kt * BK + (sw >> 1);
      __builtin_amdgcn_global_load_lds(
          (const __attribute__((address_space(1))) void*)gb,
          (__attribute__((address_space(3))) void*)(bufB + q * 8), 16, 0, 0);
    }
  };

  f32x4 acc[8][4];
#pragma unroll
  for (int m = 0; m < 8; ++m)
#pragma unroll
    for (int n = 0; n < 4; ++n) acc[m][n] = (f32x4){0.f, 0.f, 0.f, 0.f};

  const int arow = wr * 128 + (lane & 15);   // A tile row (+m*16)
  const int brow = wc * 64 + (lane & 15);    // B tile row (+n*16)
  const int kb   = (lane >> 4) << 4;         // byte offset within 64B k-slice
  const int swz  = (lane & 7) << 4;          // row&7 == lane&7 for our rows

  // ---- one tile: reads overlapped with Q0-Q2, hazard gate, stage||Q3
  auto tile = [&](int t, int do_stage) {
    const ushort* bufA = lds + (t & 1) * (2 * BM * BK);
    const ushort* bufB = bufA + BM * BK;
    const int sw0 = (kb) ^ swz;              // ks0 swizzled byte col
    const int sw1 = (64 + kb) ^ swz;         // ks1

    bf16x8 a0[8], a1[8], b0[4], b1[4];
    // quadrant-ordered issue: Q0 deps first, Q3 deps last
#pragma unroll
    for (int m = 0; m < 4; ++m)
      a0[m] = *reinterpret_cast<const bf16x8*>(bufA + (arow + m * 16) * BK + (sw0 >> 1));
#pragma unroll
    for (int n = 0; n < 4; ++n)
      b0[n] = *reinterpret_cast<const bf16x8*>(bufB + (brow + n * 16) * BK + (sw0 >> 1));
#pragma unroll
    for (int m = 4; m < 8; ++m)
      a0[m] = *reinterpret_cast<const bf16x8*>(bufA + (arow + m * 16) * BK + (sw0 >> 1));
#pragma unroll
    for (int m = 0; m < 4; ++m)
      a1[m] = *reinterpret_cast<const bf16x8*>(bufA + (arow + m * 16) * BK + (sw1 >> 1));
#pragma unroll
    for (int n = 0; n < 4; ++n)
      b1[n] = *reinterpret_cast<const bf16x8*>(bufB + (brow + n * 16) * BK + (sw1 >> 1));
#pragma unroll
    for (int m = 4; m < 8; ++m)
      a1[m] = *reinterpret_cast<const bf16x8*>(bufA + (arow + m * 16) * BK + (sw1 >> 1));

    // Q0: ks0, m0-3 (compiler inserts counted lgkmcnt before first use)
    __builtin_amdgcn_s_setprio(1);
#pragma unroll
    for (int m = 0; m < 4; ++m)
#pragma unroll
      for (int n = 0; n < 4; ++n)
        acc[m][n] = __builtin_amdgcn_mfma_f32_16x16x32_bf16(a0[m], b0[n], acc[m][n], 0, 0, 0);
    __builtin_amdgcn_s_setprio(0);
    // Q1: ks0, m4-7
    __builtin_amdgcn_s_setprio(1);
#pragma unroll
    for (int m = 4; m < 8; ++m)
#pragma unroll
      for (int n = 0; n < 4; ++n)
        acc[m][n] = __builtin_amdgcn_mfma_f32_16x16x32_bf16(a0[m], b0[n], acc[m][n], 0, 0, 0);
    __builtin_amdgcn_s_setprio(0);
    // Q2: ks1, m0-3
    __builtin_amdgcn_s_setprio(1);
#pragma unroll
    for (int m = 0; m < 4; ++m)
#pragma unroll
      for (int n = 0; n < 4; ++n)
        acc[m][n] = __builtin_amdgcn_mfma_f32_16x16x32_bf16(a1[m], b1[n], acc[m][n], 0, 0, 0);
    __builtin_amdgcn_s_setprio(0);

    // write-hazard gate: all waves' reads of buf[t&1] retired
    asm volatile("s_waitcnt lgkmcnt(0)" ::: "memory");
    __builtin_amdgcn_sched_barrier(0);
    __builtin_amdgcn_s_barrier();
    __builtin_amdgcn_sched_barrier(0);

    if (do_stage) { stageA(t + 2); stageB(t + 2); }

    // Q3: ks1, m4-7 — overlaps stage issue
    __builtin_amdgcn_s_setprio(1);
#pragma unroll
    for (int m = 4; m < 8; ++m)
#pragma unroll
      for (int n = 0; n < 4; ++n)
        acc[m][n] = __builtin_amdgcn_mfma_f32_16x16x32_bf16(a1[m], b1[n], acc[m][n], 0, 0, 0);
    __builtin_amdgcn_s_setprio(0);
  };

  // ---- prologue: stage tiles 0,1; wait tile 0 landed
  stageA(0); stageB(0);
  stageA(1); stageB(1);
  asm volatile("s_waitcnt vmcnt(8)" ::: "memory");
  __builtin_amdgcn_sched_barrier(0);
  __builtin_amdgcn_s_barrier();
  __builtin_amdgcn_sched_barrier(0);

  // ---- main loop: t = 0..13 (stage t+2, counted vmcnt(8))
  for (int t = 0; t < KSTEPS - 2; ++t) {
    tile(t, 1);
    asm volatile("s_waitcnt vmcnt(8)" ::: "memory");
    __builtin_amdgcn_sched_barrier(0);
    __builtin_amdgcn_s_barrier();
    __builtin_amdgcn_sched_barrier(0);
  }
  // ---- t = 14: no stage; tile 15 must be fully landed afterwards
  tile(KSTEPS - 2, 0);
  asm volatile("s_waitcnt vmcnt(0)" ::: "memory");
  __builtin_amdgcn_sched_barrier(0);
  __builtin_amdgcn_s_barrier();
  __builtin_amdgcn_sched_barrier(0);
  // ---- t = 15
  tile(KSTEPS - 1, 0);

  // ---- epilogue: squared block-sums. C/D: col=lane&15, row=(lane>>4)*4+reg.
#pragma unroll
  for (int m = 0; m < 8; ++m) {
    int grow = row0 + wr * 128 + m * 16;
    int v0 = grow / K_N;
    int b = (v0 + 1) * K_N;
    int rb = grow + ((lane >> 4) << 2);
#pragma unroll
    for (int np = 0; np < 2; ++np) {
      float s0 = 0.f, s1 = 0.f;
#pragma unroll
      for (int nn = 0; nn < 2; ++nn) {
        f32x4 a4 = acc[m][np * 2 + nn];
#pragma unroll
        for (int rg = 0; rg < 4; ++rg) {
          float x = a4[rg];
          float x2 = x * x;
          if (rb + rg < b) s0 += x2; else s1 += x2;
        }
      }
#pragma unroll
      for (int off = 32; off > 0; off >>= 1) {
        s0 += __shfl_xor(s0, off, 64);
        s1 += __shfl_xor(s1, off, 64);
      }
      if (lane == 0) {
        int tcol = (col0 + wc * 64 + np * 32) >> 5;
        atomicAdd(out + v0 * T_N + tcol, s0);
        if (grow + 16 > b) atomicAdd(out + (v0 + 1) * T_N + tcol, s1);
      }
    }
  }
}

// ---------------- fallback (no workspace): R1's 128x128 reg-staged kernel ---
__global__ __launch_bounds__(256) void gemm_fb(
    const float* __restrict__ imgs, const float* __restrict__ caps,
    float* __restrict__ out) {
  __shared__ ushort lds[128 * 64 + 128 * 64];
  ushort* ldsA = lds;
  ushort* ldsB = lds + 128 * 64;
  const int NBMf = MROWS / 128, NBNf = NROWS / 128;
  int orig = (int)blockIdx.x;
  int xcd = orig & 7;
  int idx = orig >> 3;
  int bm = xcd * (NBMf / 8) + (idx / NBNf);
  int bn = idx % NBNf;
  const int row0 = bm * 128, col0 = bn * 128;
  const int tid = (int)threadIdx.x, lane = tid & 63, wid = tid >> 6;
  const int wr = wid >> 1, wc = wid & 1;
  f32x4 acc[4][4];
#pragma unroll
  for (int i = 0; i < 4; ++i)
#pragma unroll
    for (int j = 0; j < 4; ++j) acc[i][j] = (f32x4){0.f, 0.f, 0.f, 0.f};
  for (int kt = 0; kt < KSTEPS; ++kt) {
#pragma unroll
    for (int it = 0; it < 4; ++it) {
      int q = it * 256 + tid;
      int r = q >> 3;
      int sw = ((q & 7) << 4) ^ ((r & 7) << 4);
      const float4* src = reinterpret_cast<const float4*>(
          imgs + (size_t)(row0 + r) * D_N + kt * BK + (sw >> 1));
      float4 f0 = src[0], f1 = src[1];
      union { ushort u[8]; int4 v4; } pk;
      pk.u[0] = f2bf(f0.x); pk.u[1] = f2bf(f0.y); pk.u[2] = f2bf(f0.z); pk.u[3] = f2bf(f0.w);
      pk.u[4] = f2bf(f1.x); pk.u[5] = f2bf(f1.y); pk.u[6] = f2bf(f1.z); pk.u[7] = f2bf(f1.w);
      *reinterpret_cast<int4*>(ldsA + q * 8) = pk.v4;
    }
#pragma unroll
    for (int it = 0; it < 4; ++it) {
      int q = it * 256 + tid;
      int r = q >> 3;
      int sw = ((q & 7) << 4) ^ ((r & 7) << 4);
      const float4* src = reinterpret_cast<const float4*>(
          caps + (size_t)(col0 + r) * D_N + kt * BK + (sw >> 1));
      float4 f0 = src[0], f1 = src[1];
      union { ushort u[8]; int4 v4; } pk;
      pk.u[0] = f2bf(f0.x); pk.u[1] = f2bf(f0.y); pk.u[2] = f2bf(f0.z); pk.u[3] = f2bf(f0.w);
      pk.u[4] = f2bf(f1.x); pk.u[5] = f2bf(f1.y); pk.u[6] = f2bf(f1.z); pk.u[7] = f2bf(f1.w);
      *reinterpret_cast<int4*>(ldsB + q * 8) = pk.v4;
    }
    __syncthreads();
#pragma unroll
    for (int ks = 0; ks < 2; ++ks) {
      bf16x8 afr[4], bfr[4];
#pragma unroll
      for (int i = 0; i < 4; ++i) {
        int r = wr * 64 + i * 16 + (lane & 15);
        int sw = (ks * 64 + (((lane >> 4) << 4))) ^ ((r & 7) << 4);
        afr[i] = *reinterpret_cast<const bf16x8*>(ldsA + r * BK + (sw >> 1));
      }
#pragma unroll
      for (int j = 0; j < 4; ++j) {
        int r = wc * 64 + j * 16 + (lane & 15);
        int sw = (ks * 64 + (((lane >> 4) << 4))) ^ ((r & 7) << 4);
        bfr[j] = *reinterpret_cast<const bf16x8*>(ldsB + r * BK + (sw >> 1));
      }
#pragma unroll
      for (int i = 0; i < 4; ++i)
#pragma unroll
        for (int j = 0; j < 4; ++j)
          acc[i][j] = __builtin_amdgcn_mfma_f32_16x16x32_bf16(afr[i], bfr[j], acc[i][j], 0, 0, 0);
    }
    __syncthreads();
  }
#pragma unroll
  for (int i = 0; i < 4; ++i) {
#pragma unroll
    for (int j = 0; j < 4; ++j) {
      f32x4 a4 = acc[i][j];
      int grow = row0 + wr * 64 + i * 16;
      int gcol = col0 + wc * 64 + j * 16;
      int t = gcol >> 5;
      int v0 = grow / K_N;
      int b = (v0 + 1) * K_N;
      int rbase = grow + ((lane >> 4) << 2);
      float s0 = 0.f, s1 = 0.f;
#pragma unroll
      for (int rg = 0; rg < 4; ++rg) {
        float x = a4[rg];
        float x2 = x * x;
        if (rbase + rg < b) s0 += x2; else s1 += x2;
      }
#pragma unroll
      for (int off = 32; off > 0; off >>= 1) {
        s0 += __shfl_xor(s0, off, 64);
        s1 += __shfl_xor(s1, off, 64);
      }
      if (lane == 0) {
        atomicAdd(out + v0 * T_N + t, s0);
        if (b < grow + 16) atomicAdd(out + (v0 + 1) * T_N + t, s1);
      }
    }
  }
}

extern "C" void kernel_launch(void* const* d_in, const int* in_sizes, int n_in,
                              void* d_out, int out_size, void* d_ws, size_t ws_size,
                              hipStream_t stream) {
  const float* imgs = (const float*)d_in[0];
  const float* caps = (const float*)d_in[1];
  float* out = (float*)d_out;

  hipMemsetAsync(d_out, 0, (size_t)V_N * T_N * sizeof(float), stream);

  const size_t need = (size_t)(MROWS + NROWS) * D_N * sizeof(ushort);  // ~36 MB

  if (ws_size >= need) {
    ushort* aws = (ushort*)d_ws;
    ushort* bws = aws + (size_t)MROWS * D_N;
    cvt_cast<<<2048, 256, 0, stream>>>(imgs, caps, aws, bws);
    gemm2<<<NWG, 512, 0, stream>>>(aws, bws, out);
  } else {
    const int nwg = (MROWS / 128) * (NROWS / 128);
    gemm_fb<<<nwg, 256, 0, stream>>>(imgs, caps, out);
  }
}

// Round 5
// 196.364 us; speedup vs baseline: 1.6584x; 1.0071x over previous
//
#include <hip/hip_runtime.h>

// Problem constants
#define V_N 256
#define T_N 256
#define K_N 36
#define L_N 32
#define D_N 1024
#define MROWS (V_N * K_N)         // 9216
#define NROWS (T_N * L_N)         // 8192
#define BM 256
#define BN 256
#define BK 64                     // bf16 elems per K-tile
#define KSTEPS (D_N / BK)         // 16
#define NBM (MROWS / BM)          // 36
#define NBN (NROWS / BN)          // 32
#define NWG (NBM * NBN)           // 1152 (divisible by 8)

typedef __attribute__((ext_vector_type(8))) short bf16x8;
typedef __attribute__((ext_vector_type(4))) float f32x4;

#define SB0 __builtin_amdgcn_sched_barrier(0)
#define BAR __builtin_amdgcn_s_barrier()
#define LGK0 asm volatile("s_waitcnt lgkmcnt(0)" ::: "memory")

__device__ __forceinline__ ushort f2bf(float x) {
  union { float f; unsigned int u; } c; c.f = x;
  unsigned int r = c.u + 0x7FFFu + ((c.u >> 16) & 1u);
  return (ushort)(r >> 16);
}

// ---------------- conversion kernel: fp32 -> bf16 workspace (flat cast) -----
__global__ void cvt_cast(const float* __restrict__ imgs, const float* __restrict__ caps,
                         ushort* __restrict__ aws, ushort* __restrict__ bws) {
  const int AQ = MROWS * (D_N / 4);
  const int BQ = NROWS * (D_N / 4);
  const int total = AQ + BQ;
  for (int q = blockIdx.x * blockDim.x + threadIdx.x; q < total;
       q += gridDim.x * blockDim.x) {
    float4 f;
    ushort4* dst;
    if (q < AQ) {
      f = reinterpret_cast<const float4*>(imgs)[q];
      dst = reinterpret_cast<ushort4*>(aws) + q;
    } else {
      f = reinterpret_cast<const float4*>(caps)[q - AQ];
      dst = reinterpret_cast<ushort4*>(bws) + (q - AQ);
    }
    ushort4 u; u.x = f2bf(f.x); u.y = f2bf(f.y); u.z = f2bf(f.z); u.w = f2bf(f.w);
    *dst = u;
  }
}

// ---------------- 256x256 8-phase-style GEMM + square + block-sum -----------
// S = A*B^T (bf16, fp32 acc); out[v,t] += sum of squares, v=arow/36, t=bcol/32.
//
// 4 phases per K-tile, each: {ds_reads; 1 stage-unit (16KB, 2 gload_lds/thr);
// barrier; lgkmcnt(0); 16 MFMA (setprio); [counted vmcnt gate]; barrier}.
// Register reuse across phases: p0 loads A(m0-3,2ks)+B(n0-1,2ks); p1 loads
// B(n2-3,2ks); p2 reloads aA with A(m4-7,2ks); p3 loads nothing.
// LDS retirement: A m0-3 rows after p0; all B after p1; all A after p2.
// Stage stream (unit = 16KB): Am47(t+1)@p0 -> buf[(t+1)&1] (retired at t-1);
// Am03(t+2)@p1, B1(t+2)@p2, B2(t+2)@p3 -> buf[t&1] retired regions.
// Gates (exact stream math): vmcnt(10) at p1-end guards Am47(t) for p2;
// vmcnt(8) at p3-end guards {Am03,B1,B2}(t+1) for p0(t+1). Tail: 8/2, 0/0.
__global__ __launch_bounds__(512, 2) void gemm2(
    const ushort* __restrict__ aws, const ushort* __restrict__ bws,
    float* __restrict__ out) {
  __shared__ ushort lds[2 * 2 * BM * BK];   // 128 KiB: 2 bufs x (A 32KB + B 32KB)

  int orig = (int)blockIdx.x;
  int wg = (orig & 7) * (NWG / 8) + (orig >> 3);   // bijective XCD swizzle
  const int bm = wg / NBN;
  const int bn = wg % NBN;
  const int row0 = bm * BM;
  const int col0 = bn * BN;

  const int tid  = (int)threadIdx.x;
  const int lane = tid & 63;
  const int wid  = tid >> 6;
  const int wr   = wid >> 2;     // 0..1  -> 128-row A slab
  const int wc   = wid & 3;      // 0..3  -> 64-row B slab

  const int kb  = (lane >> 4) << 4;   // byte offset within 64B k-slice

  // ---- stage one 16KB unit (2 gload_lds/thread). kinds:
  // 0=Am03 rows{0-63,128-191}, 1=Am47 rows{64-127,192-255},
  // 2=B1 rows{0-127}, 3=B2 rows{128-255}
  auto stage_unit = [&](int kt, int kind) {
    const int rb0 = (kind == 0) ? 0 : (kind == 1) ? 64 : (kind == 2) ? 0 : 128;
    const int rb1 = (kind == 0) ? 128 : (kind == 1) ? 192 : (kind == 2) ? 64 : 192;
    ushort* base = lds + (kt & 1) * (2 * BM * BK) + ((kind >= 2) ? BM * BK : 0);
    const ushort* g = (kind >= 2) ? bws : aws;
    const int g0 = (kind >= 2) ? col0 : row0;
#pragma unroll
    for (int j = 0; j < 2; ++j) {
      int r = (j ? rb1 : rb0) + (tid >> 3);
      int sw = ((tid & 7) << 4) ^ ((r & 7) << 4);
      const ushort* src = g + (size_t)(g0 + r) * D_N + kt * BK + (sw >> 1);
      __builtin_amdgcn_global_load_lds(
          (const __attribute__((address_space(1))) void*)src,
          (__attribute__((address_space(3))) void*)(base + r * BK + (tid & 7) * 8),
          16, 0, 0);
    }
  };

  auto rdA = [&](const ushort* bufA, int m, int ks) -> bf16x8 {
    int r = wr * 128 + m * 16 + (lane & 15);
    int sw = (ks * 64 + kb) ^ ((r & 7) << 4);
    return *reinterpret_cast<const bf16x8*>(bufA + r * BK + (sw >> 1));
  };
  auto rdB = [&](const ushort* bufB, int n, int ks) -> bf16x8 {
    int r = wc * 64 + n * 16 + (lane & 15);
    int sw = (ks * 64 + kb) ^ ((r & 7) << 4);
    return *reinterpret_cast<const bf16x8*>(bufB + r * BK + (sw >> 1));
  };

  f32x4 acc[8][4];
#pragma unroll
  for (int m = 0; m < 8; ++m)
#pragma unroll
    for (int n = 0; n < 4; ++n) acc[m][n] = (f32x4){0.f, 0.f, 0.f, 0.f};

  // ---- prologue: t0 fully + t1's {Am03,B1,B2}; gate so t0 landed
  stage_unit(0, 0); stage_unit(0, 2); stage_unit(0, 3); stage_unit(0, 1);
  stage_unit(1, 0); stage_unit(1, 2); stage_unit(1, 3);
  asm volatile("s_waitcnt vmcnt(6)" ::: "memory");
  SB0; BAR; SB0;

  // ---- main loop
  for (int t = 0; t < KSTEPS; ++t) {
    const ushort* bufA = lds + (t & 1) * (2 * BM * BK);
    const ushort* bufB = bufA + BM * BK;
    bf16x8 aA[8], b01[4], b23[4];

    // ======== p0: reads A(m0-3,2ks)+B(n0-1,2ks); stage Am47(t+1)
#pragma unroll
    for (int m = 0; m < 4; ++m) { aA[m] = rdA(bufA, m, 0); aA[4 + m] = rdA(bufA, m, 1); }
#pragma unroll
    for (int n = 0; n < 2; ++n) { b01[n] = rdB(bufB, n, 0); b01[2 + n] = rdB(bufB, n, 1); }
    if (t <= KSTEPS - 2) stage_unit(t + 1, 1);
    SB0; BAR; LGK0; SB0;
    __builtin_amdgcn_s_setprio(1);
#pragma unroll
    for (int m = 0; m < 4; ++m)
#pragma unroll
      for (int n = 0; n < 2; ++n)
        acc[m][n] = __builtin_amdgcn_mfma_f32_16x16x32_bf16(aA[m], b01[n], acc[m][n], 0, 0, 0);
#pragma unroll
    for (int m = 0; m < 4; ++m)
#pragma unroll
      for (int n = 0; n < 2; ++n)
        acc[m][n] = __builtin_amdgcn_mfma_f32_16x16x32_bf16(aA[4 + m], b01[2 + n], acc[m][n], 0, 0, 0);
    __builtin_amdgcn_s_setprio(0);
    SB0; BAR;

    // ======== p1: reads B(n2-3,2ks); stage Am03(t+2); gate vmcnt
#pragma unroll
    for (int n = 0; n < 2; ++n) { b23[n] = rdB(bufB, 2 + n, 0); b23[2 + n] = rdB(bufB, 2 + n, 1); }
    if (t <= KSTEPS - 3) stage_unit(t + 2, 0);
    SB0; BAR; LGK0; SB0;
    __builtin_amdgcn_s_setprio(1);
#pragma unroll
    for (int m = 0; m < 4; ++m)
#pragma unroll
      for (int n = 0; n < 2; ++n)
        acc[m][2 + n] = __builtin_amdgcn_mfma_f32_16x16x32_bf16(aA[m], b23[n], acc[m][2 + n], 0, 0, 0);
#pragma unroll
    for (int m = 0; m < 4; ++m)
#pragma unroll
      for (int n = 0; n < 2; ++n)
        acc[m][2 + n] = __builtin_amdgcn_mfma_f32_16x16x32_bf16(aA[4 + m], b23[2 + n], acc[m][2 + n], 0, 0, 0);
    __builtin_amdgcn_s_setprio(0);
    if (t <= KSTEPS - 3)      { asm volatile("s_waitcnt vmcnt(10)" ::: "memory"); }
    else if (t == KSTEPS - 2) { asm volatile("s_waitcnt vmcnt(8)"  ::: "memory"); }
    else                      { asm volatile("s_waitcnt vmcnt(0)"  ::: "memory"); }
    SB0; BAR;

    // ======== p2: reads A(m4-7,2ks) into aA; stage B1(t+2)
#pragma unroll
    for (int m = 0; m < 4; ++m) { aA[m] = rdA(bufA, 4 + m, 0); aA[4 + m] = rdA(bufA, 4 + m, 1); }
    if (t <= KSTEPS - 3) stage_unit(t + 2, 2);
    SB0; BAR; LGK0; SB0;
    __builtin_amdgcn_s_setprio(1);
#pragma unroll
    for (int m = 0; m < 4; ++m)
#pragma unroll
      for (int n = 0; n < 2; ++n)
        acc[4 + m][n] = __builtin_amdgcn_mfma_f32_16x16x32_bf16(aA[m], b01[n], acc[4 + m][n], 0, 0, 0);
#pragma unroll
    for (int m = 0; m < 4; ++m)
#pragma unroll
      for (int n = 0; n < 2; ++n)
        acc[4 + m][n] = __builtin_amdgcn_mfma_f32_16x16x32_bf16(aA[4 + m], b01[2 + n], acc[4 + m][n], 0, 0, 0);
    __builtin_amdgcn_s_setprio(0);
    SB0; BAR;

    // ======== p3: no reads; stage B2(t+2); gate vmcnt
    if (t <= KSTEPS - 3) stage_unit(t + 2, 3);
    SB0; BAR;
    __builtin_amdgcn_s_setprio(1);
#pragma unroll
    for (int m = 0; m < 4; ++m)
#pragma unroll
      for (int n = 0; n < 2; ++n)
        acc[4 + m][2 + n] = __builtin_amdgcn_mfma_f32_16x16x32_bf16(aA[m], b23[n], acc[4 + m][2 + n], 0, 0, 0);
#pragma unroll
    for (int m = 0; m < 4; ++m)
#pragma unroll
      for (int n = 0; n < 2; ++n)
        acc[4 + m][2 + n] = __builtin_amdgcn_mfma_f32_16x16x32_bf16(aA[4 + m], b23[2 + n], acc[4 + m][2 + n], 0, 0, 0);
    __builtin_amdgcn_s_setprio(0);
    if (t <= KSTEPS - 3)      { asm volatile("s_waitcnt vmcnt(8)" ::: "memory"); }
    else if (t == KSTEPS - 2) { asm volatile("s_waitcnt vmcnt(2)" ::: "memory"); }
    else                      { asm volatile("s_waitcnt vmcnt(0)" ::: "memory"); }
    SB0; BAR;
  }

  // ---- epilogue: squared block-sums. C/D: col=lane&15, row=(lane>>4)*4+reg.
#pragma unroll
  for (int m = 0; m < 8; ++m) {
    int grow = row0 + wr * 128 + m * 16;
    int v0 = grow / K_N;
    int b = (v0 + 1) * K_N;
    int rb = grow + ((lane >> 4) << 2);
#pragma unroll
    for (int np = 0; np < 2; ++np) {
      float s0 = 0.f, s1 = 0.f;
#pragma unroll
      for (int nn = 0; nn < 2; ++nn) {
        f32x4 a4 = acc[m][np * 2 + nn];
#pragma unroll
        for (int rg = 0; rg < 4; ++rg) {
          float x = a4[rg];
          float x2 = x * x;
          if (rb + rg < b) s0 += x2; else s1 += x2;
        }
      }
#pragma unroll
      for (int off = 32; off > 0; off >>= 1) {
        s0 += __shfl_xor(s0, off, 64);
        s1 += __shfl_xor(s1, off, 64);
      }
      if (lane == 0) {
        int tcol = (col0 + wc * 64 + np * 32) >> 5;
        atomicAdd(out + v0 * T_N + tcol, s0);
        if (grow + 16 > b) atomicAdd(out + (v0 + 1) * T_N + tcol, s1);
      }
    }
  }
}

// ---------------- fallback (no workspace): R1's 128x128 reg-staged kernel ---
__global__ __launch_bounds__(256) void gemm_fb(
    const float* __restrict__ imgs, const float* __restrict__ caps,
    float* __restrict__ out) {
  __shared__ ushort lds[128 * 64 + 128 * 64];
  ushort* ldsA = lds;
  ushort* ldsB = lds + 128 * 64;
  const int NBMf = MROWS / 128, NBNf = NROWS / 128;
  int orig = (int)blockIdx.x;
  int xcd = orig & 7;
  int idx = orig >> 3;
  int bm = xcd * (NBMf / 8) + (idx / NBNf);
  int bn = idx % NBNf;
  const int row0 = bm * 128, col0 = bn * 128;
  const int tid = (int)threadIdx.x, lane = tid & 63, wid = tid >> 6;
  const int wr = wid >> 1, wc = wid & 1;
  f32x4 acc[4][4];
#pragma unroll
  for (int i = 0; i < 4; ++i)
#pragma unroll
    for (int j = 0; j < 4; ++j) acc[i][j] = (f32x4){0.f, 0.f, 0.f, 0.f};
  for (int kt = 0; kt < KSTEPS; ++kt) {
#pragma unroll
    for (int it = 0; it < 4; ++it) {
      int q = it * 256 + tid;
      int r = q >> 3;
      int sw = ((q & 7) << 4) ^ ((r & 7) << 4);
      const float4* src = reinterpret_cast<const float4*>(
          imgs + (size_t)(row0 + r) * D_N + kt * BK + (sw >> 1));
      float4 f0 = src[0], f1 = src[1];
      union { ushort u[8]; int4 v4; } pk;
      pk.u[0] = f2bf(f0.x); pk.u[1] = f2bf(f0.y); pk.u[2] = f2bf(f0.z); pk.u[3] = f2bf(f0.w);
      pk.u[4] = f2bf(f1.x); pk.u[5] = f2bf(f1.y); pk.u[6] = f2bf(f1.z); pk.u[7] = f2bf(f1.w);
      *reinterpret_cast<int4*>(ldsA + q * 8) = pk.v4;
    }
#pragma unroll
    for (int it = 0; it < 4; ++it) {
      int q = it * 256 + tid;
      int r = q >> 3;
      int sw = ((q & 7) << 4) ^ ((r & 7) << 4);
      const float4* src = reinterpret_cast<const float4*>(
          caps + (size_t)(col0 + r) * D_N + kt * BK + (sw >> 1));
      float4 f0 = src[0], f1 = src[1];
      union { ushort u[8]; int4 v4; } pk;
      pk.u[0] = f2bf(f0.x); pk.u[1] = f2bf(f0.y); pk.u[2] = f2bf(f0.z); pk.u[3] = f2bf(f0.w);
      pk.u[4] = f2bf(f1.x); pk.u[5] = f2bf(f1.y); pk.u[6] = f2bf(f1.z); pk.u[7] = f2bf(f1.w);
      *reinterpret_cast<int4*>(ldsB + q * 8) = pk.v4;
    }
    __syncthreads();
#pragma unroll
    for (int ks = 0; ks < 2; ++ks) {
      bf16x8 afr[4], bfr[4];
#pragma unroll
      for (int i = 0; i < 4; ++i) {
        int r = wr * 64 + i * 16 + (lane & 15);
        int sw = (ks * 64 + (((lane >> 4) << 4))) ^ ((r & 7) << 4);
        afr[i] = *reinterpret_cast<const bf16x8*>(ldsA + r * BK + (sw >> 1));
      }
#pragma unroll
      for (int j = 0; j < 4; ++j) {
        int r = wc * 64 + j * 16 + (lane & 15);
        int sw = (ks * 64 + (((lane >> 4) << 4))) ^ ((r & 7) << 4);
        bfr[j] = *reinterpret_cast<const bf16x8*>(ldsB + r * BK + (sw >> 1));
      }
#pragma unroll
      for (int i = 0; i < 4; ++i)
#pragma unroll
        for (int j = 0; j < 4; ++j)
          acc[i][j] = __builtin_amdgcn_mfma_f32_16x16x32_bf16(afr[i], bfr[j], acc[i][j], 0, 0, 0);
    }
    __syncthreads();
  }
#pragma unroll
  for (int i = 0; i < 4; ++i) {
#pragma unroll
    for (int j = 0; j < 4; ++j) {
      f32x4 a4 = acc[i][j];
      int grow = row0 + wr * 64 + i * 16;
      int gcol = col0 + wc * 64 + j * 16;
      int t = gcol >> 5;
      int v0 = grow / K_N;
      int b = (v0 + 1) * K_N;
      int rbase = grow + ((lane >> 4) << 2);
      float s0 = 0.f, s1 = 0.f;
#pragma unroll
      for (int rg = 0; rg < 4; ++rg) {
        float x = a4[rg];
        float x2 = x * x;
        if (rbase + rg < b) s0 += x2; else s1 += x2;
      }
#pragma unroll
      for (int off = 32; off > 0; off >>= 1) {
        s0 += __shfl_xor(s0, off, 64);
        s1 += __shfl_xor(s1, off, 64);
      }
      if (lane == 0) {
        atomicAdd(out + v0 * T_N + t, s0);
        if (b < grow + 16) atomicAdd(out + (v0 + 1) * T_N + t, s1);
      }
    }
  }
}

extern "C" void kernel_launch(void* const* d_in, const int* in_sizes, int n_in,
                              void* d_out, int out_size, void* d_ws, size_t ws_size,
                              hipStream_t stream) {
  const float* imgs = (const float*)d_in[0];
  const float* caps = (const float*)d_in[1];
  float* out = (float*)d_out;

  hipMemsetAsync(d_out, 0, (size_t)V_N * T_N * sizeof(float), stream);

  const size_t need = (size_t)(MROWS + NROWS) * D_N * sizeof(ushort);  // ~36 MB

  if (ws_size >= need) {
    ushort* aws = (ushort*)d_ws;
    ushort* bws = aws + (size_t)MROWS * D_N;
    cvt_cast<<<2048, 256, 0, stream>>>(imgs, caps, aws, bws);
    gemm2<<<NWG, 512, 0, stream>>>(aws, bws, out);
  } else {
    const int nwg = (MROWS / 128) * (NROWS / 128);
    gemm_fb<<<nwg, 256, 0, stream>>>(imgs, caps, out);
  }
}

// Round 6
// 180.399 us; speedup vs baseline: 1.8052x; 1.0885x over previous
//
#include <hip/hip_runtime.h>

// Problem constants
#define V_N 256
#define T_N 256
#define K_N 36
#define L_N 32
#define D_N 1024
#define MROWS (V_N * K_N)         // 9216
#define NROWS (T_N * L_N)         // 8192
#define BM 256
#define BN 256
#define BK 64                     // bf16 elems per K-tile
#define KSTEPS (D_N / BK)         // 16
#define NBM (MROWS / BM)          // 36
#define NBN (NROWS / BN)          // 32
#define NWG (NBM * NBN)           // 1152 (divisible by 8)

typedef __attribute__((ext_vector_type(8))) short bf16x8;
typedef __attribute__((ext_vector_type(4))) float f32x4;

#define SB0 __builtin_amdgcn_sched_barrier(0)
#define BAR __builtin_amdgcn_s_barrier()
#define LGK0 asm volatile("s_waitcnt lgkmcnt(0)" ::: "memory")

__device__ __forceinline__ ushort f2bf(float x) {
  union { float f; unsigned int u; } c; c.f = x;
  unsigned int r = c.u + 0x7FFFu + ((c.u >> 16) & 1u);
  return (ushort)(r >> 16);
}

// ---------------- conversion kernel: fp32 -> bf16 workspace (flat cast) -----
__global__ void cvt_cast(const float* __restrict__ imgs, const float* __restrict__ caps,
                         ushort* __restrict__ aws, ushort* __restrict__ bws) {
  const int AQ = MROWS * (D_N / 4);
  const int BQ = NROWS * (D_N / 4);
  const int total = AQ + BQ;
  for (int q = blockIdx.x * blockDim.x + threadIdx.x; q < total;
       q += gridDim.x * blockDim.x) {
    float4 f;
    ushort4* dst;
    if (q < AQ) {
      f = reinterpret_cast<const float4*>(imgs)[q];
      dst = reinterpret_cast<ushort4*>(aws) + q;
    } else {
      f = reinterpret_cast<const float4*>(caps)[q - AQ];
      dst = reinterpret_cast<ushort4*>(bws) + (q - AQ);
    }
    ushort4 u; u.x = f2bf(f.x); u.y = f2bf(f.y); u.z = f2bf(f.z); u.w = f2bf(f.w);
    *dst = u;
  }
}

// ---------------- 256x256 8-phase-style GEMM + square + block-sum -----------
// S = A*B^T (bf16, fp32 acc); out[v,t] += sum of squares, v=arow/36, t=bcol/32.
//
// XCD locality (the R5 change): each XCD owns a 4-wide bn band (4 B panels =
// 2 MB, L2-resident for the XCD's whole lifetime) and sweeps bm slowly.
// B is then fetched from beyond-L2 ONCE per XCD (16 MB total) and A streams
// once per XCD (144 MB) -> beyond-L2 traffic ~160 MB vs 309 MB with the old
// bm-band mapping (B thrashed L2 every bm round).
//
// Schedule: unchanged from R4 (4 phases/K-tile, counted vmcnt, T2 swizzle,
// T5 setprio). See R4 comments for the stage-stream race math.
__global__ __launch_bounds__(512, 2) void gemm2(
    const ushort* __restrict__ aws, const ushort* __restrict__ bws,
    float* __restrict__ out) {
  __shared__ ushort lds[2 * 2 * BM * BK];   // 128 KiB: 2 bufs x (A 32KB + B 32KB)

  int orig = (int)blockIdx.x;
  // bn-band XCD swizzle: xcd owns bn in [xcd*4, xcd*4+4); bm sweeps slowly.
  // Concurrent ~32 blocks per XCD = 8 bm x 4 bn -> hot B = 4 panels (2 MB, L2-
  // resident), hot A slabs shared across the 4 bn.
  int xcd = orig & 7;
  int idx = orig >> 3;                 // 0..143
  const int bn = xcd * 4 + (idx & 3);
  const int bm = idx >> 2;             // 0..35, slow sweep
  const int row0 = bm * BM;
  const int col0 = bn * BN;

  const int tid  = (int)threadIdx.x;
  const int lane = tid & 63;
  const int wid  = tid >> 6;
  const int wr   = wid >> 2;     // 0..1  -> 128-row A slab
  const int wc   = wid & 3;      // 0..3  -> 64-row B slab

  const int kb  = (lane >> 4) << 4;   // byte offset within 64B k-slice

  // ---- stage one 16KB unit (2 gload_lds/thread). kinds:
  // 0=Am03 rows{0-63,128-191}, 1=Am47 rows{64-127,192-255},
  // 2=B1 rows{0-127}, 3=B2 rows{128-255}
  auto stage_unit = [&](int kt, int kind) {
    const int rb0 = (kind == 0) ? 0 : (kind == 1) ? 64 : (kind == 2) ? 0 : 128;
    const int rb1 = (kind == 0) ? 128 : (kind == 1) ? 192 : (kind == 2) ? 64 : 192;
    ushort* base = lds + (kt & 1) * (2 * BM * BK) + ((kind >= 2) ? BM * BK : 0);
    const ushort* g = (kind >= 2) ? bws : aws;
    const int g0 = (kind >= 2) ? col0 : row0;
#pragma unroll
    for (int j = 0; j < 2; ++j) {
      int r = (j ? rb1 : rb0) + (tid >> 3);
      int sw = ((tid & 7) << 4) ^ ((r & 7) << 4);
      const ushort* src = g + (size_t)(g0 + r) * D_N + kt * BK + (sw >> 1);
      __builtin_amdgcn_global_load_lds(
          (const __attribute__((address_space(1))) void*)src,
          (__attribute__((address_space(3))) void*)(base + r * BK + (tid & 7) * 8),
          16, 0, 0);
    }
  };

  auto rdA = [&](const ushort* bufA, int m, int ks) -> bf16x8 {
    int r = wr * 128 + m * 16 + (lane & 15);
    int sw = (ks * 64 + kb) ^ ((r & 7) << 4);
    return *reinterpret_cast<const bf16x8*>(bufA + r * BK + (sw >> 1));
  };
  auto rdB = [&](const ushort* bufB, int n, int ks) -> bf16x8 {
    int r = wc * 64 + n * 16 + (lane & 15);
    int sw = (ks * 64 + kb) ^ ((r & 7) << 4);
    return *reinterpret_cast<const bf16x8*>(bufB + r * BK + (sw >> 1));
  };

  f32x4 acc[8][4];
#pragma unroll
  for (int m = 0; m < 8; ++m)
#pragma unroll
    for (int n = 0; n < 4; ++n) acc[m][n] = (f32x4){0.f, 0.f, 0.f, 0.f};

  // ---- prologue: t0 fully + t1's {Am03,B1,B2}; gate so t0 landed
  stage_unit(0, 0); stage_unit(0, 2); stage_unit(0, 3); stage_unit(0, 1);
  stage_unit(1, 0); stage_unit(1, 2); stage_unit(1, 3);
  asm volatile("s_waitcnt vmcnt(6)" ::: "memory");
  SB0; BAR; SB0;

  // ---- main loop
  for (int t = 0; t < KSTEPS; ++t) {
    const ushort* bufA = lds + (t & 1) * (2 * BM * BK);
    const ushort* bufB = bufA + BM * BK;
    bf16x8 aA[8], b01[4], b23[4];

    // ======== p0: reads A(m0-3,2ks)+B(n0-1,2ks); stage Am47(t+1)
#pragma unroll
    for (int m = 0; m < 4; ++m) { aA[m] = rdA(bufA, m, 0); aA[4 + m] = rdA(bufA, m, 1); }
#pragma unroll
    for (int n = 0; n < 2; ++n) { b01[n] = rdB(bufB, n, 0); b01[2 + n] = rdB(bufB, n, 1); }
    if (t <= KSTEPS - 2) stage_unit(t + 1, 1);
    SB0; BAR; LGK0; SB0;
    __builtin_amdgcn_s_setprio(1);
#pragma unroll
    for (int m = 0; m < 4; ++m)
#pragma unroll
      for (int n = 0; n < 2; ++n)
        acc[m][n] = __builtin_amdgcn_mfma_f32_16x16x32_bf16(aA[m], b01[n], acc[m][n], 0, 0, 0);
#pragma unroll
    for (int m = 0; m < 4; ++m)
#pragma unroll
      for (int n = 0; n < 2; ++n)
        acc[m][n] = __builtin_amdgcn_mfma_f32_16x16x32_bf16(aA[4 + m], b01[2 + n], acc[m][n], 0, 0, 0);
    __builtin_amdgcn_s_setprio(0);
    SB0; BAR;

    // ======== p1: reads B(n2-3,2ks); stage Am03(t+2); gate vmcnt
#pragma unroll
    for (int n = 0; n < 2; ++n) { b23[n] = rdB(bufB, 2 + n, 0); b23[2 + n] = rdB(bufB, 2 + n, 1); }
    if (t <= KSTEPS - 3) stage_unit(t + 2, 0);
    SB0; BAR; LGK0; SB0;
    __builtin_amdgcn_s_setprio(1);
#pragma unroll
    for (int m = 0; m < 4; ++m)
#pragma unroll
      for (int n = 0; n < 2; ++n)
        acc[m][2 + n] = __builtin_amdgcn_mfma_f32_16x16x32_bf16(aA[m], b23[n], acc[m][2 + n], 0, 0, 0);
#pragma unroll
    for (int m = 0; m < 4; ++m)
#pragma unroll
      for (int n = 0; n < 2; ++n)
        acc[m][2 + n] = __builtin_amdgcn_mfma_f32_16x16x32_bf16(aA[4 + m], b23[2 + n], acc[m][2 + n], 0, 0, 0);
    __builtin_amdgcn_s_setprio(0);
    if (t <= KSTEPS - 3)      { asm volatile("s_waitcnt vmcnt(10)" ::: "memory"); }
    else if (t == KSTEPS - 2) { asm volatile("s_waitcnt vmcnt(8)"  ::: "memory"); }
    else                      { asm volatile("s_waitcnt vmcnt(0)"  ::: "memory"); }
    SB0; BAR;

    // ======== p2: reads A(m4-7,2ks) into aA; stage B1(t+2)
#pragma unroll
    for (int m = 0; m < 4; ++m) { aA[m] = rdA(bufA, 4 + m, 0); aA[4 + m] = rdA(bufA, 4 + m, 1); }
    if (t <= KSTEPS - 3) stage_unit(t + 2, 2);
    SB0; BAR; LGK0; SB0;
    __builtin_amdgcn_s_setprio(1);
#pragma unroll
    for (int m = 0; m < 4; ++m)
#pragma unroll
      for (int n = 0; n < 2; ++n)
        acc[4 + m][n] = __builtin_amdgcn_mfma_f32_16x16x32_bf16(aA[m], b01[n], acc[4 + m][n], 0, 0, 0);
#pragma unroll
    for (int m = 0; m < 4; ++m)
#pragma unroll
      for (int n = 0; n < 2; ++n)
        acc[4 + m][n] = __builtin_amdgcn_mfma_f32_16x16x32_bf16(aA[4 + m], b01[2 + n], acc[4 + m][n], 0, 0, 0);
    __builtin_amdgcn_s_setprio(0);
    SB0; BAR;

    // ======== p3: no reads; stage B2(t+2); gate vmcnt
    if (t <= KSTEPS - 3) stage_unit(t + 2, 3);
    SB0; BAR;
    __builtin_amdgcn_s_setprio(1);
#pragma unroll
    for (int m = 0; m < 4; ++m)
#pragma unroll
      for (int n = 0; n < 2; ++n)
        acc[4 + m][2 + n] = __builtin_amdgcn_mfma_f32_16x16x32_bf16(aA[m], b23[n], acc[4 + m][2 + n], 0, 0, 0);
#pragma unroll
    for (int m = 0; m < 4; ++m)
#pragma unroll
      for (int n = 0; n < 2; ++n)
        acc[4 + m][2 + n] = __builtin_amdgcn_mfma_f32_16x16x32_bf16(aA[4 + m], b23[2 + n], acc[4 + m][2 + n], 0, 0, 0);
    __builtin_amdgcn_s_setprio(0);
    if (t <= KSTEPS - 3)      { asm volatile("s_waitcnt vmcnt(8)" ::: "memory"); }
    else if (t == KSTEPS - 2) { asm volatile("s_waitcnt vmcnt(2)" ::: "memory"); }
    else                      { asm volatile("s_waitcnt vmcnt(0)" ::: "memory"); }
    SB0; BAR;
  }

  // ---- epilogue: squared block-sums. C/D: col=lane&15, row=(lane>>4)*4+reg.
#pragma unroll
  for (int m = 0; m < 8; ++m) {
    int grow = row0 + wr * 128 + m * 16;
    int v0 = grow / K_N;
    int b = (v0 + 1) * K_N;
    int rb = grow + ((lane >> 4) << 2);
#pragma unroll
    for (int np = 0; np < 2; ++np) {
      float s0 = 0.f, s1 = 0.f;
#pragma unroll
      for (int nn = 0; nn < 2; ++nn) {
        f32x4 a4 = acc[m][np * 2 + nn];
#pragma unroll
        for (int rg = 0; rg < 4; ++rg) {
          float x = a4[rg];
          float x2 = x * x;
          if (rb + rg < b) s0 += x2; else s1 += x2;
        }
      }
#pragma unroll
      for (int off = 32; off > 0; off >>= 1) {
        s0 += __shfl_xor(s0, off, 64);
        s1 += __shfl_xor(s1, off, 64);
      }
      if (lane == 0) {
        int tcol = (col0 + wc * 64 + np * 32) >> 5;
        atomicAdd(out + v0 * T_N + tcol, s0);
        if (grow + 16 > b) atomicAdd(out + (v0 + 1) * T_N + tcol, s1);
      }
    }
  }
}

// ---------------- fallback (no workspace): R1's 128x128 reg-staged kernel ---
__global__ __launch_bounds__(256) void gemm_fb(
    const float* __restrict__ imgs, const float* __restrict__ caps,
    float* __restrict__ out) {
  __shared__ ushort lds[128 * 64 + 128 * 64];
  ushort* ldsA = lds;
  ushort* ldsB = lds + 128 * 64;
  const int NBMf = MROWS / 128, NBNf = NROWS / 128;
  int orig = (int)blockIdx.x;
  int xcd = orig & 7;
  int idx = orig >> 3;
  int bn = xcd * (NBNf / 8) + (idx % (NBNf / 8));
  int bm = idx / (NBNf / 8);
  const int row0 = bm * 128, col0 = bn * 128;
  const int tid = (int)threadIdx.x, lane = tid & 63, wid = tid >> 6;
  const int wr = wid >> 1, wc = wid & 1;
  f32x4 acc[4][4];
#pragma unroll
  for (int i = 0; i < 4; ++i)
#pragma unroll
    for (int j = 0; j < 4; ++j) acc[i][j] = (f32x4){0.f, 0.f, 0.f, 0.f};
  for (int kt = 0; kt < KSTEPS; ++kt) {
#pragma unroll
    for (int it = 0; it < 4; ++it) {
      int q = it * 256 + tid;
      int r = q >> 3;
      int sw = ((q & 7) << 4) ^ ((r & 7) << 4);
      const float4* src = reinterpret_cast<const float4*>(
          imgs + (size_t)(row0 + r) * D_N + kt * BK + (sw >> 1));
      float4 f0 = src[0], f1 = src[1];
      union { ushort u[8]; int4 v4; } pk;
      pk.u[0] = f2bf(f0.x); pk.u[1] = f2bf(f0.y); pk.u[2] = f2bf(f0.z); pk.u[3] = f2bf(f0.w);
      pk.u[4] = f2bf(f1.x); pk.u[5] = f2bf(f1.y); pk.u[6] = f2bf(f1.z); pk.u[7] = f2bf(f1.w);
      *reinterpret_cast<int4*>(ldsA + q * 8) = pk.v4;
    }
#pragma unroll
    for (int it = 0; it < 4; ++it) {
      int q = it * 256 + tid;
      int r = q >> 3;
      int sw = ((q & 7) << 4) ^ ((r & 7) << 4);
      const float4* src = reinterpret_cast<const float4*>(
          caps + (size_t)(col0 + r) * D_N + kt * BK + (sw >> 1));
      float4 f0 = src[0], f1 = src[1];
      union { ushort u[8]; int4 v4; } pk;
      pk.u[0] = f2bf(f0.x); pk.u[1] = f2bf(f0.y); pk.u[2] = f2bf(f0.z); pk.u[3] = f2bf(f0.w);
      pk.u[4] = f2bf(f1.x); pk.u[5] = f2bf(f1.y); pk.u[6] = f2bf(f1.z); pk.u[7] = f2bf(f1.w);
      *reinterpret_cast<int4*>(ldsB + q * 8) = pk.v4;
    }
    __syncthreads();
#pragma unroll
    for (int ks = 0; ks < 2; ++ks) {
      bf16x8 afr[4], bfr[4];
#pragma unroll
      for (int i = 0; i < 4; ++i) {
        int r = wr * 64 + i * 16 + (lane & 15);
        int sw = (ks * 64 + (((lane >> 4) << 4))) ^ ((r & 7) << 4);
        afr[i] = *reinterpret_cast<const bf16x8*>(ldsA + r * BK + (sw >> 1));
      }
#pragma unroll
      for (int j = 0; j < 4; ++j) {
        int r = wc * 64 + j * 16 + (lane & 15);
        int sw = (ks * 64 + (((lane >> 4) << 4))) ^ ((r & 7) << 4);
        bfr[j] = *reinterpret_cast<const bf16x8*>(ldsB + r * BK + (sw >> 1));
      }
#pragma unroll
      for (int i = 0; i < 4; ++i)
#pragma unroll
        for (int j = 0; j < 4; ++j)
          acc[i][j] = __builtin_amdgcn_mfma_f32_16x16x32_bf16(afr[i], bfr[j], acc[i][j], 0, 0, 0);
    }
    __syncthreads();
  }
#pragma unroll
  for (int i = 0; i < 4; ++i) {
#pragma unroll
    for (int j = 0; j < 4; ++j) {
      f32x4 a4 = acc[i][j];
      int grow = row0 + wr * 64 + i * 16;
      int gcol = col0 + wc * 64 + j * 16;
      int t = gcol >> 5;
      int v0 = grow / K_N;
      int b = (v0 + 1) * K_N;
      int rbase = grow + ((lane >> 4) << 2);
      float s0 = 0.f, s1 = 0.f;
#pragma unroll
      for (int rg = 0; rg < 4; ++rg) {
        float x = a4[rg];
        float x2 = x * x;
        if (rbase + rg < b) s0 += x2; else s1 += x2;
      }
#pragma unroll
      for (int off = 32; off > 0; off >>= 1) {
        s0 += __shfl_xor(s0, off, 64);
        s1 += __shfl_xor(s1, off, 64);
      }
      if (lane == 0) {
        atomicAdd(out + v0 * T_N + t, s0);
        if (b < grow + 16) atomicAdd(out + (v0 + 1) * T_N + t, s1);
      }
    }
  }
}

extern "C" void kernel_launch(void* const* d_in, const int* in_sizes, int n_in,
                              void* d_out, int out_size, void* d_ws, size_t ws_size,
                              hipStream_t stream) {
  const float* imgs = (const float*)d_in[0];
  const float* caps = (const float*)d_in[1];
  float* out = (float*)d_out;

  hipMemsetAsync(d_out, 0, (size_t)V_N * T_N * sizeof(float), stream);

  const size_t need = (size_t)(MROWS + NROWS) * D_N * sizeof(ushort);  // ~36 MB

  if (ws_size >= need) {
    ushort* aws = (ushort*)d_ws;
    ushort* bws = aws + (size_t)MROWS * D_N;
    cvt_cast<<<2048, 256, 0, stream>>>(imgs, caps, aws, bws);
    gemm2<<<NWG, 512, 0, stream>>>(aws, bws, out);
  } else {
    const int nwg = (MROWS / 128) * (NROWS / 128);
    gemm_fb<<<nwg, 256, 0, stream>>>(imgs, caps, out);
  }
}

// Round 7
// 174.412 us; speedup vs baseline: 1.8672x; 1.0343x over previous
//
#include <hip/hip_runtime.h>

// Problem constants
#define V_N 256
#define T_N 256
#define K_N 36
#define L_N 32
#define D_N 1024
#define MROWS (V_N * K_N)         // 9216
#define NROWS (T_N * L_N)         // 8192
#define BM 256
#define BN 256
#define BK 64                     // bf16 elems per K-tile
#define KSTEPS (D_N / BK)         // 16
#define NBM (MROWS / BM)          // 36
#define NBN (NROWS / BN)          // 32
#define NWG (NBM * NBN)           // 1152 (divisible by 8)

typedef __attribute__((ext_vector_type(8))) short bf16x8;
typedef __attribute__((ext_vector_type(4))) float f32x4;

#define SB0 __builtin_amdgcn_sched_barrier(0)
#define BAR __builtin_amdgcn_s_barrier()

__device__ __forceinline__ ushort f2bf(float x) {
  union { float f; unsigned int u; } c; c.f = x;
  unsigned int r = c.u + 0x7FFFu + ((c.u >> 16) & 1u);
  return (ushort)(r >> 16);
}

// ---------------- conversion kernel: fp32 -> bf16 workspace (flat cast) -----
__global__ void cvt_cast(const float* __restrict__ imgs, const float* __restrict__ caps,
                         ushort* __restrict__ aws, ushort* __restrict__ bws) {
  const int AQ = MROWS * (D_N / 4);
  const int BQ = NROWS * (D_N / 4);
  const int total = AQ + BQ;
  for (int q = blockIdx.x * blockDim.x + threadIdx.x; q < total;
       q += gridDim.x * blockDim.x) {
    float4 f;
    ushort4* dst;
    if (q < AQ) {
      f = reinterpret_cast<const float4*>(imgs)[q];
      dst = reinterpret_cast<ushort4*>(aws) + q;
    } else {
      f = reinterpret_cast<const float4*>(caps)[q - AQ];
      dst = reinterpret_cast<ushort4*>(bws) + (q - AQ);
    }
    ushort4 u; u.x = f2bf(f.x); u.y = f2bf(f.y); u.z = f2bf(f.z); u.w = f2bf(f.w);
    *dst = u;
  }
}

// ---------------- 256x256 overlapped-phase GEMM + square + block-sum --------
// S = A*B^T (bf16, fp32 acc); out[v,t] += sum of squares, v=arow/36, t=bcol/32.
//
// R6 change: NO explicit lgkmcnt(0) anywhere in the main loop — the compiler
// emits per-operand counted lgkmcnt, so MFMA starts as soon as its first
// fragments land, overlapping the LDS drain (the R5 lockstep cost). One
// barrier per phase (after MFMA). Hazard proof: each phase's ds_reads are all
// consumed by that phase's MFMAs (operand waits force completion before the
// phase-end barrier), and every stage targets a region whose reads completed
// >=1 barrier earlier. Counted vmcnt gates unchanged from R4/R5 (proven):
// p1-end vmcnt(10) guards Am47(t) for p2; p3-end vmcnt(8) guards B2/A03/B1
// for the next tile. Tails 8/2 and 0/0. Never vmcnt(0) in steady state.
// XCD locality (R5): each XCD owns a 4-wide bn band; bm sweeps slowly.
__global__ __launch_bounds__(512, 2) void gemm2(
    const ushort* __restrict__ aws, const ushort* __restrict__ bws,
    float* __restrict__ out) {
  __shared__ ushort lds[2 * 2 * BM * BK];   // 128 KiB: 2 bufs x (A 32KB + B 32KB)

  int orig = (int)blockIdx.x;
  int xcd = orig & 7;
  int idx = orig >> 3;                 // 0..143
  const int bn = xcd * 4 + (idx & 3);
  const int bm = idx >> 2;             // 0..35, slow sweep
  const int row0 = bm * BM;
  const int col0 = bn * BN;

  const int tid  = (int)threadIdx.x;
  const int lane = tid & 63;
  const int wid  = tid >> 6;
  const int wr   = wid >> 2;     // 0..1  -> 128-row A slab
  const int wc   = wid & 3;      // 0..3  -> 64-row B slab

  const int kb  = (lane >> 4) << 4;   // byte offset within 64B k-slice

  // ---- stage one 16KB unit (2 gload_lds/thread). kinds:
  // 0=Am03 rows{0-63,128-191}, 1=Am47 rows{64-127,192-255},
  // 2=B1 rows{0-127}, 3=B2 rows{128-255}
  auto stage_unit = [&](int kt, int kind) {
    const int rb0 = (kind == 0) ? 0 : (kind == 1) ? 64 : (kind == 2) ? 0 : 128;
    const int rb1 = (kind == 0) ? 128 : (kind == 1) ? 192 : (kind == 2) ? 64 : 192;
    ushort* base = lds + (kt & 1) * (2 * BM * BK) + ((kind >= 2) ? BM * BK : 0);
    const ushort* g = (kind >= 2) ? bws : aws;
    const int g0 = (kind >= 2) ? col0 : row0;
#pragma unroll
    for (int j = 0; j < 2; ++j) {
      int r = (j ? rb1 : rb0) + (tid >> 3);
      int sw = ((tid & 7) << 4) ^ ((r & 7) << 4);
      const ushort* src = g + (size_t)(g0 + r) * D_N + kt * BK + (sw >> 1);
      __builtin_amdgcn_global_load_lds(
          (const __attribute__((address_space(1))) void*)src,
          (__attribute__((address_space(3))) void*)(base + r * BK + (tid & 7) * 8),
          16, 0, 0);
    }
  };

  auto rdA = [&](const ushort* bufA, int m, int ks) -> bf16x8 {
    int r = wr * 128 + m * 16 + (lane & 15);
    int sw = (ks * 64 + kb) ^ ((r & 7) << 4);
    return *reinterpret_cast<const bf16x8*>(bufA + r * BK + (sw >> 1));
  };
  auto rdB = [&](const ushort* bufB, int n, int ks) -> bf16x8 {
    int r = wc * 64 + n * 16 + (lane & 15);
    int sw = (ks * 64 + kb) ^ ((r & 7) << 4);
    return *reinterpret_cast<const bf16x8*>(bufB + r * BK + (sw >> 1));
  };

  f32x4 acc[8][4];
#pragma unroll
  for (int m = 0; m < 8; ++m)
#pragma unroll
    for (int n = 0; n < 4; ++n) acc[m][n] = (f32x4){0.f, 0.f, 0.f, 0.f};

  // ---- prologue: t0 fully + t1's {Am03,B1,B2}; gate so t0 landed
  stage_unit(0, 0); stage_unit(0, 2); stage_unit(0, 3); stage_unit(0, 1);
  stage_unit(1, 0); stage_unit(1, 2); stage_unit(1, 3);
  asm volatile("s_waitcnt vmcnt(6)" ::: "memory");
  SB0; BAR; SB0;

  // ---- main loop
  for (int t = 0; t < KSTEPS; ++t) {
    const ushort* bufA = lds + (t & 1) * (2 * BM * BK);
    const ushort* bufB = bufA + BM * BK;
    bf16x8 aA[8], b01[4], b23[4];

    // ======== p0: reads A(m0-3,2ks)+B(n0-1,2ks); stage Am47(t+1); MFMA m03xn01
#pragma unroll
    for (int m = 0; m < 4; ++m) { aA[m] = rdA(bufA, m, 0); aA[4 + m] = rdA(bufA, m, 1); }
#pragma unroll
    for (int n = 0; n < 2; ++n) { b01[n] = rdB(bufB, n, 0); b01[2 + n] = rdB(bufB, n, 1); }
    if (t <= KSTEPS - 2) stage_unit(t + 1, 1);
    __builtin_amdgcn_s_setprio(1);
#pragma unroll
    for (int m = 0; m < 4; ++m)
#pragma unroll
      for (int n = 0; n < 2; ++n)
        acc[m][n] = __builtin_amdgcn_mfma_f32_16x16x32_bf16(aA[m], b01[n], acc[m][n], 0, 0, 0);
#pragma unroll
    for (int m = 0; m < 4; ++m)
#pragma unroll
      for (int n = 0; n < 2; ++n)
        acc[m][n] = __builtin_amdgcn_mfma_f32_16x16x32_bf16(aA[4 + m], b01[2 + n], acc[m][n], 0, 0, 0);
    __builtin_amdgcn_s_setprio(0);
    SB0; BAR; SB0;

    // ======== p1: reads B(n2-3,2ks); stage Am03(t+2); MFMA m03xn23; gate
#pragma unroll
    for (int n = 0; n < 2; ++n) { b23[n] = rdB(bufB, 2 + n, 0); b23[2 + n] = rdB(bufB, 2 + n, 1); }
    if (t <= KSTEPS - 3) stage_unit(t + 2, 0);
    __builtin_amdgcn_s_setprio(1);
#pragma unroll
    for (int m = 0; m < 4; ++m)
#pragma unroll
      for (int n = 0; n < 2; ++n)
        acc[m][2 + n] = __builtin_amdgcn_mfma_f32_16x16x32_bf16(aA[m], b23[n], acc[m][2 + n], 0, 0, 0);
#pragma unroll
    for (int m = 0; m < 4; ++m)
#pragma unroll
      for (int n = 0; n < 2; ++n)
        acc[m][2 + n] = __builtin_amdgcn_mfma_f32_16x16x32_bf16(aA[4 + m], b23[2 + n], acc[m][2 + n], 0, 0, 0);
    __builtin_amdgcn_s_setprio(0);
    if (t <= KSTEPS - 3)      { asm volatile("s_waitcnt vmcnt(10)" ::: "memory"); }
    else if (t == KSTEPS - 2) { asm volatile("s_waitcnt vmcnt(8)"  ::: "memory"); }
    else                      { asm volatile("s_waitcnt vmcnt(0)"  ::: "memory"); }
    SB0; BAR; SB0;

    // ======== p2: reads A(m4-7,2ks); stage B1(t+2); MFMA m47xn01
#pragma unroll
    for (int m = 0; m < 4; ++m) { aA[m] = rdA(bufA, 4 + m, 0); aA[4 + m] = rdA(bufA, 4 + m, 1); }
    if (t <= KSTEPS - 3) stage_unit(t + 2, 2);
    __builtin_amdgcn_s_setprio(1);
#pragma unroll
    for (int m = 0; m < 4; ++m)
#pragma unroll
      for (int n = 0; n < 2; ++n)
        acc[4 + m][n] = __builtin_amdgcn_mfma_f32_16x16x32_bf16(aA[m], b01[n], acc[4 + m][n], 0, 0, 0);
#pragma unroll
    for (int m = 0; m < 4; ++m)
#pragma unroll
      for (int n = 0; n < 2; ++n)
        acc[4 + m][n] = __builtin_amdgcn_mfma_f32_16x16x32_bf16(aA[4 + m], b01[2 + n], acc[4 + m][n], 0, 0, 0);
    __builtin_amdgcn_s_setprio(0);
    SB0; BAR; SB0;

    // ======== p3: no reads; stage B2(t+2); MFMA m47xn23; gate
    if (t <= KSTEPS - 3) stage_unit(t + 2, 3);
    __builtin_amdgcn_s_setprio(1);
#pragma unroll
    for (int m = 0; m < 4; ++m)
#pragma unroll
      for (int n = 0; n < 2; ++n)
        acc[4 + m][2 + n] = __builtin_amdgcn_mfma_f32_16x16x32_bf16(aA[m], b23[n], acc[4 + m][2 + n], 0, 0, 0);
#pragma unroll
    for (int m = 0; m < 4; ++m)
#pragma unroll
      for (int n = 0; n < 2; ++n)
        acc[4 + m][2 + n] = __builtin_amdgcn_mfma_f32_16x16x32_bf16(aA[4 + m], b23[2 + n], acc[4 + m][2 + n], 0, 0, 0);
    __builtin_amdgcn_s_setprio(0);
    if (t <= KSTEPS - 3)      { asm volatile("s_waitcnt vmcnt(8)" ::: "memory"); }
    else if (t == KSTEPS - 2) { asm volatile("s_waitcnt vmcnt(2)" ::: "memory"); }
    else                      { asm volatile("s_waitcnt vmcnt(0)" ::: "memory"); }
    SB0; BAR; SB0;
  }

  // ---- epilogue: squared block-sums. C/D: col=lane&15, row=(lane>>4)*4+reg.
#pragma unroll
  for (int m = 0; m < 8; ++m) {
    int grow = row0 + wr * 128 + m * 16;
    int v0 = grow / K_N;
    int b = (v0 + 1) * K_N;
    int rb = grow + ((lane >> 4) << 2);
#pragma unroll
    for (int np = 0; np < 2; ++np) {
      float s0 = 0.f, s1 = 0.f;
#pragma unroll
      for (int nn = 0; nn < 2; ++nn) {
        f32x4 a4 = acc[m][np * 2 + nn];
#pragma unroll
        for (int rg = 0; rg < 4; ++rg) {
          float x = a4[rg];
          float x2 = x * x;
          if (rb + rg < b) s0 += x2; else s1 += x2;
        }
      }
#pragma unroll
      for (int off = 32; off > 0; off >>= 1) {
        s0 += __shfl_xor(s0, off, 64);
        s1 += __shfl_xor(s1, off, 64);
      }
      if (lane == 0) {
        int tcol = (col0 + wc * 64 + np * 32) >> 5;
        atomicAdd(out + v0 * T_N + tcol, s0);
        if (grow + 16 > b) atomicAdd(out + (v0 + 1) * T_N + tcol, s1);
      }
    }
  }
}

// ---------------- fallback (no workspace): R1's 128x128 reg-staged kernel ---
__global__ __launch_bounds__(256) void gemm_fb(
    const float* __restrict__ imgs, const float* __restrict__ caps,
    float* __restrict__ out) {
  __shared__ ushort lds[128 * 64 + 128 * 64];
  ushort* ldsA = lds;
  ushort* ldsB = lds + 128 * 64;
  const int NBMf = MROWS / 128, NBNf = NROWS / 128;
  int orig = (int)blockIdx.x;
  int xcd = orig & 7;
  int idx = orig >> 3;
  int bn = xcd * (NBNf / 8) + (idx % (NBNf / 8));
  int bm = idx / (NBNf / 8);
  const int row0 = bm * 128, col0 = bn * 128;
  const int tid = (int)threadIdx.x, lane = tid & 63, wid = tid >> 6;
  const int wr = wid >> 1, wc = wid & 1;
  f32x4 acc[4][4];
#pragma unroll
  for (int i = 0; i < 4; ++i)
#pragma unroll
    for (int j = 0; j < 4; ++j) acc[i][j] = (f32x4){0.f, 0.f, 0.f, 0.f};
  for (int kt = 0; kt < KSTEPS; ++kt) {
#pragma unroll
    for (int it = 0; it < 4; ++it) {
      int q = it * 256 + tid;
      int r = q >> 3;
      int sw = ((q & 7) << 4) ^ ((r & 7) << 4);
      const float4* src = reinterpret_cast<const float4*>(
          imgs + (size_t)(row0 + r) * D_N + kt * BK + (sw >> 1));
      float4 f0 = src[0], f1 = src[1];
      union { ushort u[8]; int4 v4; } pk;
      pk.u[0] = f2bf(f0.x); pk.u[1] = f2bf(f0.y); pk.u[2] = f2bf(f0.z); pk.u[3] = f2bf(f0.w);
      pk.u[4] = f2bf(f1.x); pk.u[5] = f2bf(f1.y); pk.u[6] = f2bf(f1.z); pk.u[7] = f2bf(f1.w);
      *reinterpret_cast<int4*>(ldsA + q * 8) = pk.v4;
    }
#pragma unroll
    for (int it = 0; it < 4; ++it) {
      int q = it * 256 + tid;
      int r = q >> 3;
      int sw = ((q & 7) << 4) ^ ((r & 7) << 4);
      const float4* src = reinterpret_cast<const float4*>(
          caps + (size_t)(col0 + r) * D_N + kt * BK + (sw >> 1));
      float4 f0 = src[0], f1 = src[1];
      union { ushort u[8]; int4 v4; } pk;
      pk.u[0] = f2bf(f0.x); pk.u[1] = f2bf(f0.y); pk.u[2] = f2bf(f0.z); pk.u[3] = f2bf(f0.w);
      pk.u[4] = f2bf(f1.x); pk.u[5] = f2bf(f1.y); pk.u[6] = f2bf(f1.z); pk.u[7] = f2bf(f1.w);
      *reinterpret_cast<int4*>(ldsB + q * 8) = pk.v4;
    }
    __syncthreads();
#pragma unroll
    for (int ks = 0; ks < 2; ++ks) {
      bf16x8 afr[4], bfr[4];
#pragma unroll
      for (int i = 0; i < 4; ++i) {
        int r = wr * 64 + i * 16 + (lane & 15);
        int sw = (ks * 64 + (((lane >> 4) << 4))) ^ ((r & 7) << 4);
        afr[i] = *reinterpret_cast<const bf16x8*>(ldsA + r * BK + (sw >> 1));
      }
#pragma unroll
      for (int j = 0; j < 4; ++j) {
        int r = wc * 64 + j * 16 + (lane & 15);
        int sw = (ks * 64 + (((lane >> 4) << 4))) ^ ((r & 7) << 4);
        bfr[j] = *reinterpret_cast<const bf16x8*>(ldsB + r * BK + (sw >> 1));
      }
#pragma unroll
      for (int i = 0; i < 4; ++i)
#pragma unroll
        for (int j = 0; j < 4; ++j)
          acc[i][j] = __builtin_amdgcn_mfma_f32_16x16x32_bf16(afr[i], bfr[j], acc[i][j], 0, 0, 0);
    }
    __syncthreads();
  }
#pragma unroll
  for (int i = 0; i < 4; ++i) {
#pragma unroll
    for (int j = 0; j < 4; ++j) {
      f32x4 a4 = acc[i][j];
      int grow = row0 + wr * 64 + i * 16;
      int gcol = col0 + wc * 64 + j * 16;
      int t = gcol >> 5;
      int v0 = grow / K_N;
      int b = (v0 + 1) * K_N;
      int rbase = grow + ((lane >> 4) << 2);
      float s0 = 0.f, s1 = 0.f;
#pragma unroll
      for (int rg = 0; rg < 4; ++rg) {
        float x = a4[rg];
        float x2 = x * x;
        if (rbase + rg < b) s0 += x2; else s1 += x2;
      }
#pragma unroll
      for (int off = 32; off > 0; off >>= 1) {
        s0 += __shfl_xor(s0, off, 64);
        s1 += __shfl_xor(s1, off, 64);
      }
      if (lane == 0) {
        atomicAdd(out + v0 * T_N + t, s0);
        if (b < grow + 16) atomicAdd(out + (v0 + 1) * T_N + t, s1);
      }
    }
  }
}

extern "C" void kernel_launch(void* const* d_in, const int* in_sizes, int n_in,
                              void* d_out, int out_size, void* d_ws, size_t ws_size,
                              hipStream_t stream) {
  const float* imgs = (const float*)d_in[0];
  const float* caps = (const float*)d_in[1];
  float* out = (float*)d_out;

  hipMemsetAsync(d_out, 0, (size_t)V_N * T_N * sizeof(float), stream);

  const size_t need = (size_t)(MROWS + NROWS) * D_N * sizeof(ushort);  // ~36 MB

  if (ws_size >= need) {
    ushort* aws = (ushort*)d_ws;
    ushort* bws = aws + (size_t)MROWS * D_N;
    cvt_cast<<<2048, 256, 0, stream>>>(imgs, caps, aws, bws);
    gemm2<<<NWG, 512, 0, stream>>>(aws, bws, out);
  } else {
    const int nwg = (MROWS / 128) * (NROWS / 128);
    gemm_fb<<<nwg, 256, 0, stream>>>(imgs, caps, out);
  }
}